// Round 8
// baseline (308.488 us; speedup 1.0000x reference)
//
#include <hip/hip_runtime.h>
#include <hip/hip_bf16.h>
#include <cstdint>
#include <cstddef>

#define BB 16384

typedef float  floatx4 __attribute__((ext_vector_type(4)));
typedef float  floatx2 __attribute__((ext_vector_type(2)));
typedef __bf16 bf16x8  __attribute__((ext_vector_type(8)));

__device__ __forceinline__ unsigned short f2bf(float f) {
  union { float f; unsigned int u; } v; v.f = f;
  unsigned int r = v.u + 0x7FFFu + ((v.u >> 16) & 1u);
  return (unsigned short)(r >> 16);
}
__device__ __forceinline__ float bf2f(unsigned short h) {
  union { unsigned int u; float f; } v; v.u = ((unsigned int)h) << 16;
  return v.f;
}
__device__ __forceinline__ float gelu_exact(float x) {
  return 0.5f * x * (1.0f + erff(x * 0.7071067811865475f));
}
// decode 8 fp8-e4m3 (packed in uint2) -> 8 floats via HW cvt
__device__ __forceinline__ void fp8x8_to_f32(uint2 v, float* o) {
  floatx2 p0 = __builtin_amdgcn_cvt_pk_f32_fp8((int)v.x, false);
  floatx2 p1 = __builtin_amdgcn_cvt_pk_f32_fp8((int)v.x, true);
  floatx2 p2 = __builtin_amdgcn_cvt_pk_f32_fp8((int)v.y, false);
  floatx2 p3 = __builtin_amdgcn_cvt_pk_f32_fp8((int)v.y, true);
  o[0] = p0.x; o[1] = p0.y; o[2] = p1.x; o[3] = p1.y;
  o[4] = p2.x; o[5] = p2.y; o[6] = p3.x; o[7] = p3.y;
}

// async global->LDS, 16B per lane; LDS dest = wave-uniform base + lane*16
#define ALOAD16(g, l) \
  __builtin_amdgcn_global_load_lds((const __attribute__((address_space(1))) void*)(g), \
                                   (__attribute__((address_space(3))) void*)(l), 16, 0, 0)

// ---------------------------------------------------------------------------
// k_prep: MERGED pack + transposes.
//   blocks 0..2047   : grid-stride pack jobs
//     [wallt2 18432 scalar | immb 524288 vec4 | iembf8 1467488 8-float jobs]
//     boundaries: 18432 / 542720 / 2010208
//   blocks 2048..2439: LDS-tiled transposes (w1, w2, bi_W, mm_w)
// ---------------------------------------------------------------------------
__global__ __launch_bounds__(256)
void k_prep(const float* __restrict__ gnn_W, const float* __restrict__ gnn_a,
            const float* __restrict__ item_mm, const float* __restrict__ item_emb,
            const float* __restrict__ w1, const float* __restrict__ w2,
            const float* __restrict__ bi_W, const float* __restrict__ mm_w,
            unsigned short* __restrict__ wallt2, unsigned short* __restrict__ immb,
            unsigned char* __restrict__ iembf8,
            unsigned short* __restrict__ w1t, unsigned short* __restrict__ w2t,
            unsigned short* __restrict__ biwt, unsigned short* __restrict__ mmwt)
{
  __shared__ float tile[64][65];
  if (blockIdx.x < 2048) {
    const int total = 18432 + 524288 + 1467488;   // 2010208 jobs
    for (int id = blockIdx.x * 256 + threadIdx.x; id < total; id += 2048 * 256) {
      if (id < 18432) {                  // wallt2[n][k], n < 144
        int n = id / 128, k = id % 128;
        if (n < 128) {
          wallt2[id] = f2bf(gnn_W[(n >> 5) * 4096 + k * 32 + (n & 31)]);
        } else if (n < 136) {            // q1 (128..131) / q2 (132..135)
          int h = (n - 128) & 3;
          int off = (n < 132) ? 0 : 32;
          float s = 0.f;
          for (int o = 0; o < 32; o++)
            s += gnn_W[h * 4096 + k * 32 + o] * gnn_a[h * 64 + off + o];
          wallt2[id] = f2bf(s);
        } else {
          wallt2[id] = 0;
        }
      } else if (id < 542720) {          // immb cvt vec4 (524288 jobs)
        int l = id - 18432;
        float4 v = ((const float4*)item_mm)[l];
        ushort4 o; o.x = f2bf(v.x); o.y = f2bf(v.y); o.z = f2bf(v.z); o.w = f2bf(v.w);
        ((ushort4*)immb)[l] = o;
      } else {                           // iembf8 encode, 8 floats/job (1467488)
        int l = id - 542720;
        const float4 v0 = ((const float4*)item_emb)[l * 2];
        const float4 v1 = ((const float4*)item_emb)[l * 2 + 1];
        int lo = __builtin_amdgcn_cvt_pk_fp8_f32(v0.x, v0.y, 0, false);
        lo     = __builtin_amdgcn_cvt_pk_fp8_f32(v0.z, v0.w, lo, true);
        int hi = __builtin_amdgcn_cvt_pk_fp8_f32(v1.x, v1.y, 0, false);
        hi     = __builtin_amdgcn_cvt_pk_fp8_f32(v1.z, v1.w, hi, true);
        uint2 o; o.x = (unsigned int)lo; o.y = (unsigned int)hi;
        ((uint2*)iembf8)[l] = o;
      }
    }
  } else {
    int blk = blockIdx.x - 2048;
    const float* in; unsigned short* outp; int R, C, bx, by;
    if (blk < 336)      { in = w1; outp = w1t; R = 2688; C = 512; bx = blk % 8; by = blk / 8; }
    else if (blk < 368) { blk -= 336; in = w2; outp = w2t; R = 512; C = 256; bx = blk % 4; by = blk / 4; }
    else if (blk < 388) { blk -= 368; int f = blk / 4; int r2 = blk % 4;
                          in = bi_W + f * 16384; outp = biwt + f * 16384;
                          R = 128; C = 128; bx = r2 % 2; by = r2 / 2; }
    else                { blk -= 388; in = mm_w; outp = mmwt; R = 128; C = 128;
                          bx = blk % 2; by = blk / 2; }
    const int c0 = bx * 64, r0 = by * 64;
    const int lr = threadIdx.x >> 6;
    const int lc = threadIdx.x & 63;
    #pragma unroll
    for (int i = 0; i < 16; i++) {
      int r = lr + i * 4;
      tile[r][lc] = in[(size_t)(r0 + r) * C + c0 + lc];
    }
    __syncthreads();
    #pragma unroll
    for (int i = 0; i < 16; i++) {
      int c = lr + i * 4;
      outp[(size_t)(c0 + c) * R + r0 + lc] = f2bf(tile[lc][c]);
    }
  }
}

// ---------------------------------------------------------------------------
// k_featmm: MERGED feature build + mm GEMM/LN/GELU (disjoint xb rows).
//   blocks 0..2047   : feat — 8 batches/block (one wave each); quarter-wave
//                      fp8 gathers (8 B/lane covers a 128 B row with 16 lanes)
//   blocks 2048..2303: mmln — y = item_mm @ mm_w + b -> LN -> GELU -> xb row 4
// ---------------------------------------------------------------------------
__global__ __launch_bounds__(512)
void k_featmm(const int* __restrict__ item_id, const int* __restrict__ likes,
              const int* __restrict__ views, const int* __restrict__ item_seq,
              const unsigned char* __restrict__ iembf8, const float* __restrict__ cate_emb,
              const unsigned short* __restrict__ immb, const unsigned short* __restrict__ mmwt,
              const float* __restrict__ mm_b, const float* __restrict__ ln_g,
              const float* __restrict__ ln_b, unsigned short* __restrict__ xb)
{
  __shared__ __align__(16) char smem[64 * 130 * 4];    // mmln only
  const int t = threadIdx.x, lane = t & 63, w = t >> 6;

  if (blockIdx.x < 2048) {
    // ------------------ feat: one wave per batch row ------------------
    const int b = blockIdx.x * 8 + w;
    const int g = lane >> 4, l16 = lane & 15;
    const size_t base = (size_t)b * 768;
    const int li = likes[b], vi = views[b], id = item_id[b];

    const int ng = (g < 2) ? 13 : 12;
    int idxs[13];
    #pragma unroll
    for (int e = 0; e < 13; e++)
      idxs[e] = (e < ng) ? item_seq[b * 50 + g + 4 * e] : 0;

    float acc[8] = {0.f, 0.f, 0.f, 0.f, 0.f, 0.f, 0.f, 0.f};
    float cnt = 0.f;
    #pragma unroll
    for (int e = 0; e < 13; e++) {
      const int idx = idxs[e];
      if (idx != 0) {
        cnt += 1.0f;
        uint2 v = *(const uint2*)&iembf8[(size_t)idx * 128 + l16 * 8];
        float dv[8];
        fp8x8_to_f32(v, dv);
        #pragma unroll
        for (int k = 0; k < 8; k++) acc[k] += dv[k];
      }
    }
    #pragma unroll
    for (int k = 0; k < 8; k++) {
      acc[k] += __shfl_xor(acc[k], 16, 64);
      acc[k] += __shfl_xor(acc[k], 32, 64);
    }
    cnt += __shfl_xor(cnt, 16, 64);
    cnt += __shfl_xor(cnt, 32, 64);
    const float ic = 1.0f / fmaxf(cnt, 1.0f);

    *(unsigned int*)&xb[base + lane * 2] = 0u;          // row 0 zeros

    if (g == 0) {                                       // row 5: hist mean
      uint4 o;
      o.x = (unsigned int)f2bf(acc[0] * ic) | ((unsigned int)f2bf(acc[1] * ic) << 16);
      o.y = (unsigned int)f2bf(acc[2] * ic) | ((unsigned int)f2bf(acc[3] * ic) << 16);
      o.z = (unsigned int)f2bf(acc[4] * ic) | ((unsigned int)f2bf(acc[5] * ic) << 16);
      o.w = (unsigned int)f2bf(acc[6] * ic) | ((unsigned int)f2bf(acc[7] * ic) << 16);
      *(uint4*)&xb[base + 640 + l16 * 8] = o;
    } else if (g == 1) {                                // row 3: id (fp8 -> bf16)
      uint2 v = *(const uint2*)&iembf8[(size_t)id * 128 + l16 * 8];
      float dv[8];
      fp8x8_to_f32(v, dv);
      uint4 o;
      o.x = (unsigned int)f2bf(dv[0]) | ((unsigned int)f2bf(dv[1]) << 16);
      o.y = (unsigned int)f2bf(dv[2]) | ((unsigned int)f2bf(dv[3]) << 16);
      o.z = (unsigned int)f2bf(dv[4]) | ((unsigned int)f2bf(dv[5]) << 16);
      o.w = (unsigned int)f2bf(dv[6]) | ((unsigned int)f2bf(dv[7]) << 16);
      *(uint4*)&xb[base + 384 + l16 * 8] = o;
    } else {                                            // rows 1/2: like/view
      const int ci = (g == 2) ? li : vi;
      const float4 v0 = *(const float4*)&cate_emb[(size_t)ci * 128 + l16 * 8];
      const float4 v1 = *(const float4*)&cate_emb[(size_t)ci * 128 + l16 * 8 + 4];
      uint4 o;
      o.x = (unsigned int)f2bf(v0.x) | ((unsigned int)f2bf(v0.y) << 16);
      o.y = (unsigned int)f2bf(v0.z) | ((unsigned int)f2bf(v0.w) << 16);
      o.z = (unsigned int)f2bf(v1.x) | ((unsigned int)f2bf(v1.y) << 16);
      o.w = (unsigned int)f2bf(v1.z) | ((unsigned int)f2bf(v1.w) << 16);
      *(uint4*)&xb[base + 128 + (g - 2) * 128 + l16 * 8] = o;
    }
    return;
  }

  // ------------------ mmln: 64x128 GEMM + bias + LN + GELU ------------------
  unsigned short* As = (unsigned short*)smem;           // 64*64
  unsigned short* Bs = (unsigned short*)(smem + 8192);  // 128*64
  float* cls = (float*)smem;                            // 64*130 after barrier

  const int lr = lane & 15, lq = lane >> 4;
  const int m0 = (blockIdx.x - 2048) * 64;

  floatx4 acc[4];
  #pragma unroll
  for (int a = 0; a < 4; a++) acc[a] = (floatx4){0.f, 0.f, 0.f, 0.f};

  const int srow = lane >> 3;
  const int schk = (lane & 7) ^ srow;
  const int rb0 = w * 24;

  for (int k0 = 0; k0 < 128; k0 += 64) {
    __syncthreads();
    #pragma unroll
    for (int q = 0; q < 3; q++) {
      const int rb = rb0 + q * 8;
      if (rb < 64) ALOAD16(immb + (size_t)(m0 + rb + srow) * 128 + k0 + schk * 8, As + rb * 64);
      else { const int rbb = rb - 64; ALOAD16(mmwt + (size_t)(rbb + srow) * 128 + k0 + schk * 8, Bs + rbb * 64); }
    }
    __syncthreads();
    #pragma unroll
    for (int ko = 0; ko < 2; ko++) {
      bf16x8 af[4], bv;
      #pragma unroll
      for (int mt = 0; mt < 4; mt++) {
        const int row = mt * 16 + lr;
        const int pc = (ko * 4 + lq) ^ (lr & 7);
        af[mt] = __builtin_bit_cast(bf16x8, *(const uint4*)&As[row * 64 + pc * 8]);
      }
      {
        const int row = w * 16 + lr;
        const int pc = (ko * 4 + lq) ^ (lr & 7);
        bv = __builtin_bit_cast(bf16x8, *(const uint4*)&Bs[row * 64 + pc * 8]);
      }
      #pragma unroll
      for (int mt = 0; mt < 4; mt++)
        acc[mt] = __builtin_amdgcn_mfma_f32_16x16x32_bf16(af[mt], bv, acc[mt], 0, 0, 0);
    }
  }

  __syncthreads();
  #pragma unroll
  for (int mt = 0; mt < 4; mt++)
    #pragma unroll
    for (int i = 0; i < 4; i++) {
      const int rr = mt * 16 + lq * 4 + i;
      const int cc = w * 16 + lr;
      cls[rr * 130 + cc] = acc[mt][i] + mm_b[cc];
    }
  __syncthreads();

  const float2 g2 = *(const float2*)&ln_g[lane * 2];
  const float2 b2 = *(const float2*)&ln_b[lane * 2];
  #pragma unroll
  for (int rr = 0; rr < 8; rr++) {
    const int r = w * 8 + rr;
    float2 v = *(const float2*)&cls[r * 130 + lane * 2];
    float s = v.x + v.y, s2 = v.x * v.x + v.y * v.y;
    #pragma unroll
    for (int o = 32; o > 0; o >>= 1) { s += __shfl_xor(s, o, 64); s2 += __shfl_xor(s2, o, 64); }
    float mu  = s * (1.0f / 128.0f);
    float var = s2 * (1.0f / 128.0f) - mu * mu;
    float rs  = rsqrtf(var + 1e-5f);
    float t0 = gelu_exact((v.x - mu) * rs * g2.x + b2.x);
    float t1 = gelu_exact((v.y - mu) * rs * g2.y + b2.y);
    unsigned int pk = (unsigned int)f2bf(t0) | ((unsigned int)f2bf(t1) << 16);
    *(unsigned int*)&xb[(size_t)(m0 + r) * 768 + 512 + lane * 2] = pk;
  }
}

// ---------------------------------------------------------------------------
// MLP1 GEMM: h1 = gelu(bn1(c @ w1 + b1)).  128x128 tile, BK=64, 512 thr,
// 8 waves 2x4.  XOR-8 swizzled global_load_lds staging (0-conflict layout).
// R2-PROVEN: minimum 2-phase prefetch — double-buffered LDS (2 x 32 KB,
// 2 WG/CU), stage K-tile t+1 BEFORE computing tile t, single __syncthreads
// (vmcnt(0) drain) per K-tile placed AFTER compute.  ~48 us / MfmaUtil 40%
// = the documented 2-barrier-structure ceiling (913 TF).  Do not touch.
// ---------------------------------------------------------------------------
__global__ __launch_bounds__(512)
void gemm_mlp1(const unsigned short* __restrict__ A, const unsigned short* __restrict__ Bt,
               unsigned short* __restrict__ Cp,
               const float* __restrict__ bias, const float* __restrict__ bng,
               const float* __restrict__ bnb)
{
  int p = blockIdx.y * gridDim.x + blockIdx.x;
  int xcd = p & 7, slot = p >> 3;
  const int bx = slot % gridDim.x;
  const int by = xcd * (gridDim.y >> 3) + slot / gridDim.x;
  const int n0 = bx * 128;
  const int m0 = by * 128;

  __shared__ __align__(16) unsigned short lds[2 * 16384];   // 2 slots x 32 KB
  const int t = threadIdx.x, lane = t & 63, w = t >> 6;
  const int wm = w & 1, wn = w >> 1;          // 2 x 4
  const int lr = lane & 15, lq = lane >> 4;

  floatx4 acc[4][2];
  #pragma unroll
  for (int a = 0; a < 4; a++)
    #pragma unroll
    for (int b = 0; b < 2; b++) acc[a][b] = (floatx4){0.f, 0.f, 0.f, 0.f};

  const int srow = lane >> 3;
  const int schk = (lane & 7) ^ srow;
  const int rb0 = w * 32;

  // stage K-tile (k-offset k0) into LDS slot s
  auto STAGE = [&](int k0, int s) {
    unsigned short* Ad = lds + s * 16384;
    unsigned short* Bd = Ad + 8192;
    #pragma unroll
    for (int q = 0; q < 4; q++) {
      const int rb = rb0 + q * 8;
      if (rb < 128) {
        ALOAD16(A + (size_t)(m0 + rb + srow) * 2688 + k0 + schk * 8, Ad + rb * 64);
      } else {
        ALOAD16(Bt + (size_t)(n0 + rb - 128 + srow) * 2688 + k0 + schk * 8, Bd + (rb - 128) * 64);
      }
    }
  };

  STAGE(0, 0);
  __syncthreads();                              // tile 0 resident

  for (int kt = 0; kt < 42; kt++) {
    const int cur = kt & 1;
    if (kt < 41) STAGE((kt + 1) * 64, cur ^ 1); // prefetch next tile (in flight)
    const unsigned short* As = lds + cur * 16384;
    const unsigned short* Bs = As + 8192;
    #pragma unroll
    for (int ko = 0; ko < 2; ko++) {
      bf16x8 af[4], bfv[2];
      #pragma unroll
      for (int mt = 0; mt < 4; mt++) {
        const int row = wm * 64 + mt * 16 + lr;
        const int pc = (ko * 4 + lq) ^ (lr & 7);
        af[mt] = __builtin_bit_cast(bf16x8, *(const uint4*)&As[row * 64 + pc * 8]);
      }
      #pragma unroll
      for (int nt = 0; nt < 2; nt++) {
        const int row = wn * 32 + nt * 16 + lr;
        const int pc = (ko * 4 + lq) ^ (lr & 7);
        bfv[nt] = __builtin_bit_cast(bf16x8, *(const uint4*)&Bs[row * 64 + pc * 8]);
      }
      #pragma unroll
      for (int mt = 0; mt < 4; mt++)
        #pragma unroll
        for (int nt = 0; nt < 2; nt++)
          acc[mt][nt] = __builtin_amdgcn_mfma_f32_16x16x32_bf16(af[mt], bfv[nt], acc[mt][nt], 0, 0, 0);
    }
    __syncthreads();                            // drains vmcnt(0): next tile landed,
  }                                             // current slot free for re-stage

  #pragma unroll
  for (int mt = 0; mt < 4; mt++)
    #pragma unroll
    for (int nt = 0; nt < 2; nt++)
      #pragma unroll
      for (int i = 0; i < 4; i++) {
        const int cm = m0 + wm * 64 + mt * 16 + lq * 4 + i;
        const int cn = n0 + wn * 32 + nt * 16 + lr;
        float tt = acc[mt][nt][i] + bias[cn];
        tt = tt * (bng[cn] * 0.9999950000374997f) + bnb[cn];
        Cp[(size_t)cm * 512 + cn] = f2bf(gelu_exact(tt));
      }
}

// ---------------------------------------------------------------------------
// Fused: hp GEMM (96x144x128, ei/ej as fused columns 128..135) -> GAT
// attention + ELU + SE -> c[:, :768] + fused vid GEMM + pairs -> c[:, 768:].
// R6-BEST (68.4 us measured): per z: vid GEMM -> barrier -> vacc bf16 into
// vids[16][132] -> barrier -> vectorized ushort4 epilogue.  R7's barrier-free
// variant regressed (75 us) — kernel is latency-bound; interior reshuffles
// don't help.  Restored verbatim; do not touch further.
// ---------------------------------------------------------------------------
__global__ __launch_bounds__(256)
void k_hpatt(const unsigned short* __restrict__ xb, const unsigned short* __restrict__ wallt2,
             const float* __restrict__ se_w1, const float* __restrict__ se_b1,
             const float* __restrict__ se_w2, const float* __restrict__ se_b2,
             const unsigned short* __restrict__ biwt,
             unsigned short* __restrict__ c)
{
  __shared__ __align__(16) char smem[34944];             // 30720 stage/hps + 4224 vids
  unsigned short* As = (unsigned short*)smem;            // 96*64  = 12288 B
  unsigned short* Bs = (unsigned short*)(smem + 12288);  // 144*64 = 18432 B
  unsigned short* hps = (unsigned short*)smem;           // 96*146 bf16 (alias)
  unsigned short* vids = (unsigned short*)(smem + 30720);// 16*132 bf16 vid[z] tile

  const int t = threadIdx.x, lane = t & 63, w = t >> 6;
  const int wm = w & 1, wn = w >> 1;                     // both in {0,1}
  const int lr = lane & 15, lq = lane >> 4;
  const int m0 = blockIdx.x * 96;

  floatx4 acc[3][5];
  #pragma unroll
  for (int a = 0; a < 3; a++)
    #pragma unroll
    for (int b = 0; b < 5; b++) acc[a][b] = (floatx4){0.f, 0.f, 0.f, 0.f};

  const int srow = lane >> 3;
  const int schk = (lane & 7) ^ srow;

  for (int k0 = 0; k0 < 128; k0 += 64) {
    __syncthreads();
    #pragma unroll
    for (int q = 0; q < 8; q++) {
      const int e = w + 4 * q;          // 30 issues: A rows 96 (12), B rows 144 (18)
      if (e < 30) {
        const int rb = e * 8;
        if (rb < 96) {
          ALOAD16(xb + (size_t)(m0 + rb + srow) * 128 + k0 + schk * 8, As + rb * 64);
        } else {
          const int rbb = rb - 96;
          ALOAD16(wallt2 + (size_t)(rbb + srow) * 128 + k0 + schk * 8, Bs + rbb * 64);
        }
      }
    }
    __syncthreads();
    #pragma unroll
    for (int ko = 0; ko < 2; ko++) {
      bf16x8 af[3];
      #pragma unroll
      for (int mt = 0; mt < 3; mt++) {
        const int row = wm * 48 + mt * 16 + lr;
        const int pc = (ko * 4 + lq) ^ (lr & 7);
        af[mt] = __builtin_bit_cast(bf16x8, *(const uint4*)&As[row * 64 + pc * 8]);
      }
      #pragma unroll
      for (int nt = 0; nt < 5; nt++) {
        if (nt < 4 || wn == 0) {
          const int tid = wn + 2 * nt;  // wn0: 0,2,4,6,8 ; wn1: 1,3,5,7
          const int row = tid * 16 + lr;
          const int pc = (ko * 4 + lq) ^ (lr & 7);
          bf16x8 bfv = __builtin_bit_cast(bf16x8, *(const uint4*)&Bs[row * 64 + pc * 8]);
          #pragma unroll
          for (int mt = 0; mt < 3; mt++)
            acc[mt][nt] = __builtin_amdgcn_mfma_f32_16x16x32_bf16(af[mt], bfv, acc[mt][nt], 0, 0, 0);
        }
      }
    }
  }

  __syncthreads();                     // staging dead; write bf16 hp tile (146 stride)
  #pragma unroll
  for (int mt = 0; mt < 3; mt++)
    #pragma unroll
    for (int nt = 0; nt < 5; nt++)
      if (nt < 4 || wn == 0) {
        const int tid = wn + 2 * nt;
        #pragma unroll
        for (int i = 0; i < 4; i++) {
          const int rr = wm * 48 + mt * 16 + lq * 4 + i;
          const int cc = tid * 16 + lr;
          hps[rr * 146 + cc] = f2bf(acc[mt][nt][i]);
        }
      }
  __syncthreads();

  const int hh = lane >> 4;            // head of col pair (2l, 2l+1)

  for (int it = 0; it < 4; it++) {
    const int lb = w * 4 + it;
    const int b = blockIdx.x * 16 + lb;
    unsigned short* hb = hps + lb * 6 * 146;   // this wave's exclusive rows

    float2 vm[6];
    float ein[6], ejn[6];
    #pragma unroll
    for (int m = 0; m < 6; m++) {
      unsigned int pk = *(const unsigned int*)&hb[m * 146 + lane * 2];
      vm[m].x = bf2f((unsigned short)(pk & 0xFFFFu));
      vm[m].y = bf2f((unsigned short)(pk >> 16));
      ein[m] = bf2f(hb[m * 146 + 128 + hh]);
      ejn[m] = bf2f(hb[m * 146 + 132 + hh]);
    }

    float g0[6], g1[6], zz[6];
    #pragma unroll
    for (int n = 0; n < 6; n++) {
      float ev[6]; float mx = -1e30f;
      #pragma unroll
      for (int m = 0; m < 6; m++) {
        float e = ein[n] + ejn[m];
        e = e > 0.f ? e : 0.2f * e;
        ev[m] = e; mx = fmaxf(mx, e);
      }
      float ss = 0.f;
      #pragma unroll
      for (int m = 0; m < 6; m++) { ev[m] = __expf(ev[m] - mx); ss += ev[m]; }
      const float inv = 1.0f / ss;
      float hn0 = 0.f, hn1 = 0.f;
      #pragma unroll
      for (int m = 0; m < 6; m++) {
        const float a = ev[m] * inv;
        hn0 += a * vm[m].x; hn1 += a * vm[m].y;
      }
      unsigned int xp = *(const unsigned int*)&xb[(size_t)b * 768 + n * 128 + lane * 2];
      float A0 = hn0 + bf2f((unsigned short)(xp & 0xFFFFu));
      float A1 = hn1 + bf2f((unsigned short)(xp >> 16));
      A0 = A0 > 0.f ? A0 : __expf(A0) - 1.0f;     // ELU, fast exp
      A1 = A1 > 0.f ? A1 : __expf(A1) - 1.0f;
      g0[n] = A0; g1[n] = A1;
      float zacc = A0 + A1;
      #pragma unroll
      for (int o = 32; o > 0; o >>= 1) zacc += __shfl_xor(zacc, o, 64);
      zz[n] = zacc * (1.0f / 128.0f);
    }

    float rr3[3];
    #pragma unroll
    for (int j = 0; j < 3; j++) {
      float a = se_b1[j];
      #pragma unroll
      for (int n = 0; n < 6; n++) a += zz[n] * se_w1[n * 3 + j];
      rr3[j] = fmaxf(a, 0.f);
    }
    float wse[6];
    #pragma unroll
    for (int n = 0; n < 6; n++) {
      float a = se_b2[n];
      #pragma unroll
      for (int j = 0; j < 3; j++) a += rr3[j] * se_w2[j * 6 + n];
      wse[n] = 1.0f / (1.0f + __expf(-a));
    }

    #pragma unroll
    for (int n = 0; n < 6; n++) {
      unsigned int pc = (unsigned int)f2bf(g0[n]) | ((unsigned int)f2bf(g1[n]) << 16);
      unsigned int ps = (unsigned int)f2bf(g0[n] * wse[n]) | ((unsigned int)f2bf(g1[n] * wse[n]) << 16);
      *(unsigned int*)&c[(size_t)b * 2688 + n * 128 + lane * 2] = pc;
      // s written IN PLACE into hps (this wave's rows, already read above)
      *(unsigned int*)&hb[n * 146 + lane * 2] = ps;
    }
  }

  // ---------------- fused vid GEMM + pairs (vectorized tail) ----------------
  __syncthreads();                     // all 16 batches' s resident in hps
  {
    const size_t B0 = (size_t)blockIdx.x * 16;
    const int pb0c[5] = {0, 5, 9, 12, 14};
    for (int z = 0; z < 5; z++) {
      floatx4 vacc[2];
      vacc[0] = (floatx4){0.f, 0.f, 0.f, 0.f};
      vacc[1] = (floatx4){0.f, 0.f, 0.f, 0.f};
      #pragma unroll
      for (int kk = 0; kk < 4; kk++) {
        // A-frag: s[batch=lr][feat z][k = kk*32 + lq*8 .. +8] via 4 aligned u32
        const int abase = (lr * 6 + z) * 146 + kk * 32 + lq * 8;
        uint4 au;
        au.x = *(const unsigned int*)&hps[abase + 0];
        au.y = *(const unsigned int*)&hps[abase + 2];
        au.z = *(const unsigned int*)&hps[abase + 4];
        au.w = *(const unsigned int*)&hps[abase + 6];
        const bf16x8 af = __builtin_bit_cast(bf16x8, au);
        #pragma unroll
        for (int nt = 0; nt < 2; nt++) {
          const int col = (w + nt * 4) * 16 + lr;        // output dim e
          const bf16x8 bv = __builtin_bit_cast(bf16x8,
            *(const uint4*)&biwt[z * 16384 + col * 128 + kk * 32 + lq * 8]);
          vacc[nt] = __builtin_amdgcn_mfma_f32_16x16x32_bf16(af, bv, vacc[nt], 0, 0, 0);
        }
      }
      __syncthreads();                 // prior z's vids readers done (no-op z=0)
      #pragma unroll
      for (int nt = 0; nt < 2; nt++) {
        const int cc = (w + nt * 4) * 16 + lr;
        #pragma unroll
        for (int i = 0; i < 4; i++)
          vids[(lq * 4 + i) * 132 + cc] = f2bf(vacc[nt][i]);
      }
      __syncthreads();                 // vids[z] resident
      const int npairs = 5 - z;
      const int tot = 16 * 32 * npairs;
      for (int e = t; e < tot; e += 256) {
        const int g  = e & 31;
        const int rp = e >> 5;
        const int p  = rp % npairs;
        const int r  = rp / npairs;
        ushort4 vv = *(const ushort4*)&vids[r * 132 + g * 4];
        const int hb2 = (r * 6 + z + 1 + p) * 146 + g * 4;
        unsigned int s01 = *(const unsigned int*)&hps[hb2];
        unsigned int s23 = *(const unsigned int*)&hps[hb2 + 2];
        ushort4 o;
        o.x = f2bf(bf2f(vv.x) * bf2f((unsigned short)(s01 & 0xFFFFu)));
        o.y = f2bf(bf2f(vv.y) * bf2f((unsigned short)(s01 >> 16)));
        o.z = f2bf(bf2f(vv.z) * bf2f((unsigned short)(s23 & 0xFFFFu)));
        o.w = f2bf(bf2f(vv.w) * bf2f((unsigned short)(s23 >> 16)));
        *(ushort4*)&c[(B0 + r) * 2688 + 768 + (size_t)(pb0c[z] + p) * 128 + g * 4] = o;
      }
    }
  }
}

// ---------------------------------------------------------------------------
// Fused MLP2 + bn+gelu + final 256-dot + sigmoid -> out.
// ROUND 8: M=32 tile, 512 blocks = 2 WG/CU (was M=64/256 blocks = 1 WG/CU
// with ZERO inter-WG overlap — the R1-proven pathology).  8 waves cover the
// 16 N-tiles (acc[2][2]/wave); prefetch-1 dbuf unchanged (2 x 36 KB = 72 KB,
// 2 WG/CU = 144 KB <= 160 KB).  Same XOR-8 swizzle; arithmetic identical.
// ---------------------------------------------------------------------------
__global__ __launch_bounds__(512)
void k_mlp2out(const unsigned short* __restrict__ A, const unsigned short* __restrict__ Bt,
               const float* __restrict__ b2v, const float* __restrict__ bng,
               const float* __restrict__ bnb, const float* __restrict__ w3,
               const float* __restrict__ b3, float* __restrict__ out)
{
  __shared__ __align__(16) unsigned short smem[2 * 18432];  // 2 slots x 36 KB
  unsigned short* h2s = smem;                    // alias slot 0 after K-loop (32*264)

  const int t = threadIdx.x, lane = t & 63, w = t >> 6;
  const int lr = lane & 15, lq = lane >> 4;
  const int m0 = blockIdx.x * 32;

  floatx4 acc[2][2];
  #pragma unroll
  for (int a = 0; a < 2; a++)
    #pragma unroll
    for (int b = 0; b < 2; b++) acc[a][b] = (floatx4){0.f, 0.f, 0.f, 0.f};

  const int srow = lane >> 3;
  const int schk = (lane & 7) ^ srow;

  // slot s: As_ = 32x64 (2048 ush), Bs_ = 256x64 (16384 ush) -> 18432 ush
  // stage plan: 36 8-row chunks (A: 0..3, B: 4..35) over 8 waves x 5 issues
  auto STAGE = [&](int k0, int s) {
    unsigned short* As_ = smem + s * 18432;
    unsigned short* Bs_ = As_ + 2048;
    #pragma unroll
    for (int q = 0; q < 5; q++) {
      const int e = w + 8 * q;
      if (e < 36) {
        if (e < 4) {
          const int rb = e * 8;
          ALOAD16(A + (size_t)(m0 + rb + srow) * 512 + k0 + schk * 8, As_ + rb * 64);
        } else {
          const int rbb = (e - 4) * 8;
          ALOAD16(Bt + (size_t)(rbb + srow) * 512 + k0 + schk * 8, Bs_ + rbb * 64);
        }
      }
    }
  };

  STAGE(0, 0);
  __syncthreads();                              // tile 0 resident

  for (int kt = 0; kt < 8; kt++) {
    const int cur = kt & 1;
    if (kt < 7) STAGE((kt + 1) * 64, cur ^ 1);  // prefetch next tile (in flight)
    const unsigned short* As = smem + cur * 18432;
    const unsigned short* Bs = As + 2048;
    #pragma unroll
    for (int ko = 0; ko < 2; ko++) {
      bf16x8 af[2], bfv[2];
      #pragma unroll
      for (int mt = 0; mt < 2; mt++) {
        const int row = mt * 16 + lr;
        const int pc = (ko * 4 + lq) ^ (lr & 7);
        af[mt] = __builtin_bit_cast(bf16x8, *(const uint4*)&As[row * 64 + pc * 8]);
      }
      #pragma unroll
      for (int nt = 0; nt < 2; nt++) {
        const int row = (w * 2 + nt) * 16 + lr;
        const int pc = (ko * 4 + lq) ^ (lr & 7);
        bfv[nt] = __builtin_bit_cast(bf16x8, *(const uint4*)&Bs[row * 64 + pc * 8]);
      }
      #pragma unroll
      for (int mt = 0; mt < 2; mt++)
        #pragma unroll
        for (int nt = 0; nt < 2; nt++)
          acc[mt][nt] = __builtin_amdgcn_mfma_f32_16x16x32_bf16(af[mt], bfv[nt], acc[mt][nt], 0, 0, 0);
    }
    __syncthreads();                            // next tile landed; slot reusable
  }

  #pragma unroll
  for (int mt = 0; mt < 2; mt++)
    #pragma unroll
    for (int nt = 0; nt < 2; nt++)
      #pragma unroll
      for (int i = 0; i < 4; i++) {
        const int rr = mt * 16 + lq * 4 + i;
        const int cc = (w * 2 + nt) * 16 + lr;
        float tt = acc[mt][nt][i] + b2v[cc];
        tt = tt * (bng[cc] * 0.9999950000374997f) + bnb[cc];
        h2s[rr * 264 + cc] = f2bf(gelu_exact(tt));
      }
  __syncthreads();

  const float4 w4 = *(const float4*)&w3[lane * 4];
  #pragma unroll
  for (int rr = 0; rr < 4; rr++) {
    const int r = w * 4 + rr;
    ushort4 v = *(const ushort4*)&h2s[r * 264 + lane * 4];
    float a = bf2f(v.x) * w4.x + bf2f(v.y) * w4.y + bf2f(v.z) * w4.z + bf2f(v.w) * w4.w;
    #pragma unroll
    for (int o = 32; o > 0; o >>= 1) a += __shfl_xor(a, o, 64);
    if (lane == 0) out[m0 + r] = 1.0f / (1.0f + __expf(-(a + b3[0])));
  }
}

// ---------------------------------------------------------------------------
// Workspace layout (bytes).  sb buffer no longer used (vid fused into hpatt).
// ---------------------------------------------------------------------------
#define OFF_MMWT   0ull           // 32768
#define OFF_BIWT   65536ull       // 163840
#define OFF_W1T    229376ull      // 2752512
#define OFF_W2T    2981888ull     // 262144
#define OFF_IMMB   3244032ull     // 4194304
#define OFF_XB     7438336ull     // 25165824  (alias: h1 later)
#define OFF_SB     57769984ull    // 25165824 (unused after fusion)
#define OFF_C      82935808ull    // 88080384
#define OFF_IEMB   179404800ull   // 11739904 (fp8)
#define OFF_WALLT2 191144704ull   // 36864 -> total 191181568

extern "C" void kernel_launch(void* const* d_in, const int* in_sizes, int n_in,
                              void* d_out, int out_size, void* d_ws, size_t ws_size,
                              hipStream_t stream)
{
  const int*   item_id  = (const int*)  d_in[0];
  const float* item_mm  = (const float*)d_in[1];
  const int*   likes    = (const int*)  d_in[2];
  const int*   views    = (const int*)  d_in[3];
  const int*   item_seq = (const int*)  d_in[4];
  const float* item_emb = (const float*)d_in[5];
  const float* cate_emb = (const float*)d_in[6];
  const float* mm_w     = (const float*)d_in[7];
  const float* mm_b     = (const float*)d_in[8];
  const float* ln_g     = (const float*)d_in[9];
  const float* ln_b     = (const float*)d_in[10];
  const float* gnn_W    = (const float*)d_in[11];
  const float* gnn_a    = (const float*)d_in[12];
  const float* se_w1    = (const float*)d_in[13];
  const float* se_b1    = (const float*)d_in[14];
  const float* se_w2    = (const float*)d_in[15];
  const float* se_b2    = (const float*)d_in[16];
  const float* bi_W     = (const float*)d_in[17];
  const float* mlp_w1   = (const float*)d_in[18];
  const float* mlp_b1   = (const float*)d_in[19];
  const float* bn1_g    = (const float*)d_in[20];
  const float* bn1_b    = (const float*)d_in[21];
  const float* mlp_w2   = (const float*)d_in[22];
  const float* mlp_b2   = (const float*)d_in[23];
  const float* bn2_g    = (const float*)d_in[24];
  const float* bn2_b    = (const float*)d_in[25];
  const float* mlp_w3   = (const float*)d_in[26];
  const float* mlp_b3   = (const float*)d_in[27];
  float* out = (float*)d_out;

  char* ws = (char*)d_ws;
  unsigned short* mmwt   = (unsigned short*)(ws + OFF_MMWT);
  unsigned short* biwt   = (unsigned short*)(ws + OFF_BIWT);
  unsigned short* w1t    = (unsigned short*)(ws + OFF_W1T);
  unsigned short* w2t    = (unsigned short*)(ws + OFF_W2T);
  unsigned short* immb   = (unsigned short*)(ws + OFF_IMMB);
  unsigned short* xb     = (unsigned short*)(ws + OFF_XB);
  unsigned short* cbuf   = (unsigned short*)(ws + OFF_C);
  unsigned short* h1b    = (unsigned short*)(ws + OFF_XB);   // alias: xb dead after k_hpatt
  unsigned char*  iembf8 = (unsigned char*) (ws + OFF_IEMB);
  unsigned short* wallt2 = (unsigned short*)(ws + OFF_WALLT2);

  // 1. merged packs + transposes (item_emb -> fp8 e4m3 table)
  k_prep<<<2440, 256, 0, stream>>>(gnn_W, gnn_a, item_mm, item_emb,
                                   mlp_w1, mlp_w2, bi_W, mm_w,
                                   wallt2, immb, iembf8, w1t, w2t, biwt, mmwt);
  // 2. merged feature build (fp8 gathers) + mm GEMM/LN/GELU
  k_featmm<<<2304, 512, 0, stream>>>(item_id, likes, views, item_seq, iembf8, cate_emb,
                                     immb, mmwt, mm_b, ln_g, ln_b, xb);
  // 3. fused hp GEMM + attention + SE + vid GEMM + pairs -> c (full width)
  k_hpatt<<<1024, 256, 0, stream>>>(xb, wallt2, se_w1, se_b1, se_w2, se_b2,
                                    biwt, cbuf);
  // 4. MLP1: h1 = gelu(bn1(c @ w1 + b1)), 2-phase prefetch, dbuf LDS (R2)
  gemm_mlp1<<<dim3(4, 128), 512, 0, stream>>>(cbuf, w1t, h1b, mlp_b1, bn1_g, bn1_b);
  // 5. fused MLP2: M=32 tile, 512 blocks = 2 WG/CU, prefetch-1 dbuf
  k_mlp2out<<<512, 512, 0, stream>>>(h1b, w2t, mlp_b2, bn2_g, bn2_b, mlp_w3, mlp_b3, out);
}

// Round 9
// 303.678 us; speedup vs baseline: 1.0158x; 1.0158x over previous
//
#include <hip/hip_runtime.h>
#include <hip/hip_bf16.h>
#include <cstdint>
#include <cstddef>

#define BB 16384

typedef float  floatx4 __attribute__((ext_vector_type(4)));
typedef float  floatx2 __attribute__((ext_vector_type(2)));
typedef __bf16 bf16x8  __attribute__((ext_vector_type(8)));

__device__ __forceinline__ unsigned short f2bf(float f) {
  union { float f; unsigned int u; } v; v.f = f;
  unsigned int r = v.u + 0x7FFFu + ((v.u >> 16) & 1u);
  return (unsigned short)(r >> 16);
}
__device__ __forceinline__ float bf2f(unsigned short h) {
  union { unsigned int u; float f; } v; v.u = ((unsigned int)h) << 16;
  return v.f;
}
__device__ __forceinline__ float gelu_exact(float x) {
  return 0.5f * x * (1.0f + erff(x * 0.7071067811865475f));
}
// decode 8 fp8-e4m3 (packed in uint2) -> 8 floats via HW cvt
__device__ __forceinline__ void fp8x8_to_f32(uint2 v, float* o) {
  floatx2 p0 = __builtin_amdgcn_cvt_pk_f32_fp8((int)v.x, false);
  floatx2 p1 = __builtin_amdgcn_cvt_pk_f32_fp8((int)v.x, true);
  floatx2 p2 = __builtin_amdgcn_cvt_pk_f32_fp8((int)v.y, false);
  floatx2 p3 = __builtin_amdgcn_cvt_pk_f32_fp8((int)v.y, true);
  o[0] = p0.x; o[1] = p0.y; o[2] = p1.x; o[3] = p1.y;
  o[4] = p2.x; o[5] = p2.y; o[6] = p3.x; o[7] = p3.y;
}

// async global->LDS, 16B per lane; LDS dest = wave-uniform base + lane*16
#define ALOAD16(g, l) \
  __builtin_amdgcn_global_load_lds((const __attribute__((address_space(1))) void*)(g), \
                                   (__attribute__((address_space(3))) void*)(l), 16, 0, 0)

// ---------------------------------------------------------------------------
// k_prep: MERGED pack + transposes.
//   blocks 0..2047   : grid-stride pack jobs
//     [wallt2 18432 scalar | immb 524288 vec4 | iembf8 1467488 8-float jobs]
//     boundaries: 18432 / 542720 / 2010208
//   blocks 2048..2439: LDS-tiled transposes (w1, w2, bi_W, mm_w)
// ---------------------------------------------------------------------------
__global__ __launch_bounds__(256)
void k_prep(const float* __restrict__ gnn_W, const float* __restrict__ gnn_a,
            const float* __restrict__ item_mm, const float* __restrict__ item_emb,
            const float* __restrict__ w1, const float* __restrict__ w2,
            const float* __restrict__ bi_W, const float* __restrict__ mm_w,
            unsigned short* __restrict__ wallt2, unsigned short* __restrict__ immb,
            unsigned char* __restrict__ iembf8,
            unsigned short* __restrict__ w1t, unsigned short* __restrict__ w2t,
            unsigned short* __restrict__ biwt, unsigned short* __restrict__ mmwt)
{
  __shared__ float tile[64][65];
  if (blockIdx.x < 2048) {
    const int total = 18432 + 524288 + 1467488;   // 2010208 jobs
    for (int id = blockIdx.x * 256 + threadIdx.x; id < total; id += 2048 * 256) {
      if (id < 18432) {                  // wallt2[n][k], n < 144
        int n = id / 128, k = id % 128;
        if (n < 128) {
          wallt2[id] = f2bf(gnn_W[(n >> 5) * 4096 + k * 32 + (n & 31)]);
        } else if (n < 136) {            // q1 (128..131) / q2 (132..135)
          int h = (n - 128) & 3;
          int off = (n < 132) ? 0 : 32;
          float s = 0.f;
          for (int o = 0; o < 32; o++)
            s += gnn_W[h * 4096 + k * 32 + o] * gnn_a[h * 64 + off + o];
          wallt2[id] = f2bf(s);
        } else {
          wallt2[id] = 0;
        }
      } else if (id < 542720) {          // immb cvt vec4 (524288 jobs)
        int l = id - 18432;
        float4 v = ((const float4*)item_mm)[l];
        ushort4 o; o.x = f2bf(v.x); o.y = f2bf(v.y); o.z = f2bf(v.z); o.w = f2bf(v.w);
        ((ushort4*)immb)[l] = o;
      } else {                           // iembf8 encode, 8 floats/job (1467488)
        int l = id - 542720;
        const float4 v0 = ((const float4*)item_emb)[l * 2];
        const float4 v1 = ((const float4*)item_emb)[l * 2 + 1];
        int lo = __builtin_amdgcn_cvt_pk_fp8_f32(v0.x, v0.y, 0, false);
        lo     = __builtin_amdgcn_cvt_pk_fp8_f32(v0.z, v0.w, lo, true);
        int hi = __builtin_amdgcn_cvt_pk_fp8_f32(v1.x, v1.y, 0, false);
        hi     = __builtin_amdgcn_cvt_pk_fp8_f32(v1.z, v1.w, hi, true);
        uint2 o; o.x = (unsigned int)lo; o.y = (unsigned int)hi;
        ((uint2*)iembf8)[l] = o;
      }
    }
  } else {
    int blk = blockIdx.x - 2048;
    const float* in; unsigned short* outp; int R, C, bx, by;
    if (blk < 336)      { in = w1; outp = w1t; R = 2688; C = 512; bx = blk % 8; by = blk / 8; }
    else if (blk < 368) { blk -= 336; in = w2; outp = w2t; R = 512; C = 256; bx = blk % 4; by = blk / 4; }
    else if (blk < 388) { blk -= 368; int f = blk / 4; int r2 = blk % 4;
                          in = bi_W + f * 16384; outp = biwt + f * 16384;
                          R = 128; C = 128; bx = r2 % 2; by = r2 / 2; }
    else                { blk -= 388; in = mm_w; outp = mmwt; R = 128; C = 128;
                          bx = blk % 2; by = blk / 2; }
    const int c0 = bx * 64, r0 = by * 64;
    const int lr = threadIdx.x >> 6;
    const int lc = threadIdx.x & 63;
    #pragma unroll
    for (int i = 0; i < 16; i++) {
      int r = lr + i * 4;
      tile[r][lc] = in[(size_t)(r0 + r) * C + c0 + lc];
    }
    __syncthreads();
    #pragma unroll
    for (int i = 0; i < 16; i++) {
      int c = lr + i * 4;
      outp[(size_t)(c0 + c) * R + r0 + lc] = f2bf(tile[lc][c]);
    }
  }
}

// ---------------------------------------------------------------------------
// k_featmm: MERGED feature build + mm GEMM/LN/GELU (disjoint xb rows).
//   blocks 0..2047   : feat — 8 batches/block (one wave each); quarter-wave
//                      fp8 gathers (8 B/lane covers a 128 B row with 16 lanes)
//   blocks 2048..2303: mmln — y = item_mm @ mm_w + b -> LN -> GELU -> xb row 4
// ---------------------------------------------------------------------------
__global__ __launch_bounds__(512)
void k_featmm(const int* __restrict__ item_id, const int* __restrict__ likes,
              const int* __restrict__ views, const int* __restrict__ item_seq,
              const unsigned char* __restrict__ iembf8, const float* __restrict__ cate_emb,
              const unsigned short* __restrict__ immb, const unsigned short* __restrict__ mmwt,
              const float* __restrict__ mm_b, const float* __restrict__ ln_g,
              const float* __restrict__ ln_b, unsigned short* __restrict__ xb)
{
  __shared__ __align__(16) char smem[64 * 130 * 4];    // mmln only
  const int t = threadIdx.x, lane = t & 63, w = t >> 6;

  if (blockIdx.x < 2048) {
    // ------------------ feat: one wave per batch row ------------------
    const int b = blockIdx.x * 8 + w;
    const int g = lane >> 4, l16 = lane & 15;
    const size_t base = (size_t)b * 768;
    const int li = likes[b], vi = views[b], id = item_id[b];

    const int ng = (g < 2) ? 13 : 12;
    int idxs[13];
    #pragma unroll
    for (int e = 0; e < 13; e++)
      idxs[e] = (e < ng) ? item_seq[b * 50 + g + 4 * e] : 0;

    float acc[8] = {0.f, 0.f, 0.f, 0.f, 0.f, 0.f, 0.f, 0.f};
    float cnt = 0.f;
    #pragma unroll
    for (int e = 0; e < 13; e++) {
      const int idx = idxs[e];
      if (idx != 0) {
        cnt += 1.0f;
        uint2 v = *(const uint2*)&iembf8[(size_t)idx * 128 + l16 * 8];
        float dv[8];
        fp8x8_to_f32(v, dv);
        #pragma unroll
        for (int k = 0; k < 8; k++) acc[k] += dv[k];
      }
    }
    #pragma unroll
    for (int k = 0; k < 8; k++) {
      acc[k] += __shfl_xor(acc[k], 16, 64);
      acc[k] += __shfl_xor(acc[k], 32, 64);
    }
    cnt += __shfl_xor(cnt, 16, 64);
    cnt += __shfl_xor(cnt, 32, 64);
    const float ic = 1.0f / fmaxf(cnt, 1.0f);

    *(unsigned int*)&xb[base + lane * 2] = 0u;          // row 0 zeros

    if (g == 0) {                                       // row 5: hist mean
      uint4 o;
      o.x = (unsigned int)f2bf(acc[0] * ic) | ((unsigned int)f2bf(acc[1] * ic) << 16);
      o.y = (unsigned int)f2bf(acc[2] * ic) | ((unsigned int)f2bf(acc[3] * ic) << 16);
      o.z = (unsigned int)f2bf(acc[4] * ic) | ((unsigned int)f2bf(acc[5] * ic) << 16);
      o.w = (unsigned int)f2bf(acc[6] * ic) | ((unsigned int)f2bf(acc[7] * ic) << 16);
      *(uint4*)&xb[base + 640 + l16 * 8] = o;
    } else if (g == 1) {                                // row 3: id (fp8 -> bf16)
      uint2 v = *(const uint2*)&iembf8[(size_t)id * 128 + l16 * 8];
      float dv[8];
      fp8x8_to_f32(v, dv);
      uint4 o;
      o.x = (unsigned int)f2bf(dv[0]) | ((unsigned int)f2bf(dv[1]) << 16);
      o.y = (unsigned int)f2bf(dv[2]) | ((unsigned int)f2bf(dv[3]) << 16);
      o.z = (unsigned int)f2bf(dv[4]) | ((unsigned int)f2bf(dv[5]) << 16);
      o.w = (unsigned int)f2bf(dv[6]) | ((unsigned int)f2bf(dv[7]) << 16);
      *(uint4*)&xb[base + 384 + l16 * 8] = o;
    } else {                                            // rows 1/2: like/view
      const int ci = (g == 2) ? li : vi;
      const float4 v0 = *(const float4*)&cate_emb[(size_t)ci * 128 + l16 * 8];
      const float4 v1 = *(const float4*)&cate_emb[(size_t)ci * 128 + l16 * 8 + 4];
      uint4 o;
      o.x = (unsigned int)f2bf(v0.x) | ((unsigned int)f2bf(v0.y) << 16);
      o.y = (unsigned int)f2bf(v0.z) | ((unsigned int)f2bf(v0.w) << 16);
      o.z = (unsigned int)f2bf(v1.x) | ((unsigned int)f2bf(v1.y) << 16);
      o.w = (unsigned int)f2bf(v1.z) | ((unsigned int)f2bf(v1.w) << 16);
      *(uint4*)&xb[base + 128 + (g - 2) * 128 + l16 * 8] = o;
    }
    return;
  }

  // ------------------ mmln: 64x128 GEMM + bias + LN + GELU ------------------
  unsigned short* As = (unsigned short*)smem;           // 64*64
  unsigned short* Bs = (unsigned short*)(smem + 8192);  // 128*64
  float* cls = (float*)smem;                            // 64*130 after barrier

  const int lr = lane & 15, lq = lane >> 4;
  const int m0 = (blockIdx.x - 2048) * 64;

  floatx4 acc[4];
  #pragma unroll
  for (int a = 0; a < 4; a++) acc[a] = (floatx4){0.f, 0.f, 0.f, 0.f};

  const int srow = lane >> 3;
  const int schk = (lane & 7) ^ srow;
  const int rb0 = w * 24;

  for (int k0 = 0; k0 < 128; k0 += 64) {
    __syncthreads();
    #pragma unroll
    for (int q = 0; q < 3; q++) {
      const int rb = rb0 + q * 8;
      if (rb < 64) ALOAD16(immb + (size_t)(m0 + rb + srow) * 128 + k0 + schk * 8, As + rb * 64);
      else { const int rbb = rb - 64; ALOAD16(mmwt + (size_t)(rbb + srow) * 128 + k0 + schk * 8, Bs + rbb * 64); }
    }
    __syncthreads();
    #pragma unroll
    for (int ko = 0; ko < 2; ko++) {
      bf16x8 af[4], bv;
      #pragma unroll
      for (int mt = 0; mt < 4; mt++) {
        const int row = mt * 16 + lr;
        const int pc = (ko * 4 + lq) ^ (lr & 7);
        af[mt] = __builtin_bit_cast(bf16x8, *(const uint4*)&As[row * 64 + pc * 8]);
      }
      {
        const int row = w * 16 + lr;
        const int pc = (ko * 4 + lq) ^ (lr & 7);
        bv = __builtin_bit_cast(bf16x8, *(const uint4*)&Bs[row * 64 + pc * 8]);
      }
      #pragma unroll
      for (int mt = 0; mt < 4; mt++)
        acc[mt] = __builtin_amdgcn_mfma_f32_16x16x32_bf16(af[mt], bv, acc[mt], 0, 0, 0);
    }
  }

  __syncthreads();
  #pragma unroll
  for (int mt = 0; mt < 4; mt++)
    #pragma unroll
    for (int i = 0; i < 4; i++) {
      const int rr = mt * 16 + lq * 4 + i;
      const int cc = w * 16 + lr;
      cls[rr * 130 + cc] = acc[mt][i] + mm_b[cc];
    }
  __syncthreads();

  const float2 g2 = *(const float2*)&ln_g[lane * 2];
  const float2 b2 = *(const float2*)&ln_b[lane * 2];
  #pragma unroll
  for (int rr = 0; rr < 8; rr++) {
    const int r = w * 8 + rr;
    float2 v = *(const float2*)&cls[r * 130 + lane * 2];
    float s = v.x + v.y, s2 = v.x * v.x + v.y * v.y;
    #pragma unroll
    for (int o = 32; o > 0; o >>= 1) { s += __shfl_xor(s, o, 64); s2 += __shfl_xor(s2, o, 64); }
    float mu  = s * (1.0f / 128.0f);
    float var = s2 * (1.0f / 128.0f) - mu * mu;
    float rs  = rsqrtf(var + 1e-5f);
    float t0 = gelu_exact((v.x - mu) * rs * g2.x + b2.x);
    float t1 = gelu_exact((v.y - mu) * rs * g2.y + b2.y);
    unsigned int pk = (unsigned int)f2bf(t0) | ((unsigned int)f2bf(t1) << 16);
    *(unsigned int*)&xb[(size_t)(m0 + r) * 768 + 512 + lane * 2] = pk;
  }
}

// ---------------------------------------------------------------------------
// MLP1 GEMM: h1 = gelu(bn1(c @ w1 + b1)).  128x128 tile, BK=64, 512 thr,
// 8 waves 2x4.  XOR-8 swizzled global_load_lds staging (0-conflict layout).
// R2-PROVEN: minimum 2-phase prefetch — double-buffered LDS (2 x 32 KB,
// 2 WG/CU), stage K-tile t+1 BEFORE computing tile t, single __syncthreads
// (vmcnt(0) drain) per K-tile placed AFTER compute.  ~48 us / MfmaUtil 40%
// = the documented 2-barrier-structure ceiling (913 TF).  Do not touch.
// ---------------------------------------------------------------------------
__global__ __launch_bounds__(512)
void gemm_mlp1(const unsigned short* __restrict__ A, const unsigned short* __restrict__ Bt,
               unsigned short* __restrict__ Cp,
               const float* __restrict__ bias, const float* __restrict__ bng,
               const float* __restrict__ bnb)
{
  int p = blockIdx.y * gridDim.x + blockIdx.x;
  int xcd = p & 7, slot = p >> 3;
  const int bx = slot % gridDim.x;
  const int by = xcd * (gridDim.y >> 3) + slot / gridDim.x;
  const int n0 = bx * 128;
  const int m0 = by * 128;

  __shared__ __align__(16) unsigned short lds[2 * 16384];   // 2 slots x 32 KB
  const int t = threadIdx.x, lane = t & 63, w = t >> 6;
  const int wm = w & 1, wn = w >> 1;          // 2 x 4
  const int lr = lane & 15, lq = lane >> 4;

  floatx4 acc[4][2];
  #pragma unroll
  for (int a = 0; a < 4; a++)
    #pragma unroll
    for (int b = 0; b < 2; b++) acc[a][b] = (floatx4){0.f, 0.f, 0.f, 0.f};

  const int srow = lane >> 3;
  const int schk = (lane & 7) ^ srow;
  const int rb0 = w * 32;

  // stage K-tile (k-offset k0) into LDS slot s
  auto STAGE = [&](int k0, int s) {
    unsigned short* Ad = lds + s * 16384;
    unsigned short* Bd = Ad + 8192;
    #pragma unroll
    for (int q = 0; q < 4; q++) {
      const int rb = rb0 + q * 8;
      if (rb < 128) {
        ALOAD16(A + (size_t)(m0 + rb + srow) * 2688 + k0 + schk * 8, Ad + rb * 64);
      } else {
        ALOAD16(Bt + (size_t)(n0 + rb - 128 + srow) * 2688 + k0 + schk * 8, Bd + (rb - 128) * 64);
      }
    }
  };

  STAGE(0, 0);
  __syncthreads();                              // tile 0 resident

  for (int kt = 0; kt < 42; kt++) {
    const int cur = kt & 1;
    if (kt < 41) STAGE((kt + 1) * 64, cur ^ 1); // prefetch next tile (in flight)
    const unsigned short* As = lds + cur * 16384;
    const unsigned short* Bs = As + 8192;
    #pragma unroll
    for (int ko = 0; ko < 2; ko++) {
      bf16x8 af[4], bfv[2];
      #pragma unroll
      for (int mt = 0; mt < 4; mt++) {
        const int row = wm * 64 + mt * 16 + lr;
        const int pc = (ko * 4 + lq) ^ (lr & 7);
        af[mt] = __builtin_bit_cast(bf16x8, *(const uint4*)&As[row * 64 + pc * 8]);
      }
      #pragma unroll
      for (int nt = 0; nt < 2; nt++) {
        const int row = wn * 32 + nt * 16 + lr;
        const int pc = (ko * 4 + lq) ^ (lr & 7);
        bfv[nt] = __builtin_bit_cast(bf16x8, *(const uint4*)&Bs[row * 64 + pc * 8]);
      }
      #pragma unroll
      for (int mt = 0; mt < 4; mt++)
        #pragma unroll
        for (int nt = 0; nt < 2; nt++)
          acc[mt][nt] = __builtin_amdgcn_mfma_f32_16x16x32_bf16(af[mt], bfv[nt], acc[mt][nt], 0, 0, 0);
    }
    __syncthreads();                            // drains vmcnt(0): next tile landed,
  }                                             // current slot free for re-stage

  #pragma unroll
  for (int mt = 0; mt < 4; mt++)
    #pragma unroll
    for (int nt = 0; nt < 2; nt++)
      #pragma unroll
      for (int i = 0; i < 4; i++) {
        const int cm = m0 + wm * 64 + mt * 16 + lq * 4 + i;
        const int cn = n0 + wn * 32 + nt * 16 + lr;
        float tt = acc[mt][nt][i] + bias[cn];
        tt = tt * (bng[cn] * 0.9999950000374997f) + bnb[cn];
        Cp[(size_t)cm * 512 + cn] = f2bf(gelu_exact(tt));
      }
}

// ---------------------------------------------------------------------------
// Fused: hp GEMM (96x144x128, ei/ej as fused columns 128..135) -> GAT
// attention + ELU + SE -> c[:, :768] + fused vid GEMM + pairs -> c[:, 768:].
// R6-BEST (68.4-68.9 us, twice reproduced): per z: vid GEMM -> barrier ->
// vacc bf16 into vids[16][132] -> barrier -> vectorized ushort4 epilogue.
// R7's barrier-free variant regressed (75 us) — latency-bound; interior
// reshuffles don't help.  Do not touch further.
// ---------------------------------------------------------------------------
__global__ __launch_bounds__(256)
void k_hpatt(const unsigned short* __restrict__ xb, const unsigned short* __restrict__ wallt2,
             const float* __restrict__ se_w1, const float* __restrict__ se_b1,
             const float* __restrict__ se_w2, const float* __restrict__ se_b2,
             const unsigned short* __restrict__ biwt,
             unsigned short* __restrict__ c)
{
  __shared__ __align__(16) char smem[34944];             // 30720 stage/hps + 4224 vids
  unsigned short* As = (unsigned short*)smem;            // 96*64  = 12288 B
  unsigned short* Bs = (unsigned short*)(smem + 12288);  // 144*64 = 18432 B
  unsigned short* hps = (unsigned short*)smem;           // 96*146 bf16 (alias)
  unsigned short* vids = (unsigned short*)(smem + 30720);// 16*132 bf16 vid[z] tile

  const int t = threadIdx.x, lane = t & 63, w = t >> 6;
  const int wm = w & 1, wn = w >> 1;                     // both in {0,1}
  const int lr = lane & 15, lq = lane >> 4;
  const int m0 = blockIdx.x * 96;

  floatx4 acc[3][5];
  #pragma unroll
  for (int a = 0; a < 3; a++)
    #pragma unroll
    for (int b = 0; b < 5; b++) acc[a][b] = (floatx4){0.f, 0.f, 0.f, 0.f};

  const int srow = lane >> 3;
  const int schk = (lane & 7) ^ srow;

  for (int k0 = 0; k0 < 128; k0 += 64) {
    __syncthreads();
    #pragma unroll
    for (int q = 0; q < 8; q++) {
      const int e = w + 4 * q;          // 30 issues: A rows 96 (12), B rows 144 (18)
      if (e < 30) {
        const int rb = e * 8;
        if (rb < 96) {
          ALOAD16(xb + (size_t)(m0 + rb + srow) * 128 + k0 + schk * 8, As + rb * 64);
        } else {
          const int rbb = rb - 96;
          ALOAD16(wallt2 + (size_t)(rbb + srow) * 128 + k0 + schk * 8, Bs + rbb * 64);
        }
      }
    }
    __syncthreads();
    #pragma unroll
    for (int ko = 0; ko < 2; ko++) {
      bf16x8 af[3];
      #pragma unroll
      for (int mt = 0; mt < 3; mt++) {
        const int row = wm * 48 + mt * 16 + lr;
        const int pc = (ko * 4 + lq) ^ (lr & 7);
        af[mt] = __builtin_bit_cast(bf16x8, *(const uint4*)&As[row * 64 + pc * 8]);
      }
      #pragma unroll
      for (int nt = 0; nt < 5; nt++) {
        if (nt < 4 || wn == 0) {
          const int tid = wn + 2 * nt;  // wn0: 0,2,4,6,8 ; wn1: 1,3,5,7
          const int row = tid * 16 + lr;
          const int pc = (ko * 4 + lq) ^ (lr & 7);
          bf16x8 bfv = __builtin_bit_cast(bf16x8, *(const uint4*)&Bs[row * 64 + pc * 8]);
          #pragma unroll
          for (int mt = 0; mt < 3; mt++)
            acc[mt][nt] = __builtin_amdgcn_mfma_f32_16x16x32_bf16(af[mt], bfv, acc[mt][nt], 0, 0, 0);
        }
      }
    }
  }

  __syncthreads();                     // staging dead; write bf16 hp tile (146 stride)
  #pragma unroll
  for (int mt = 0; mt < 3; mt++)
    #pragma unroll
    for (int nt = 0; nt < 5; nt++)
      if (nt < 4 || wn == 0) {
        const int tid = wn + 2 * nt;
        #pragma unroll
        for (int i = 0; i < 4; i++) {
          const int rr = wm * 48 + mt * 16 + lq * 4 + i;
          const int cc = tid * 16 + lr;
          hps[rr * 146 + cc] = f2bf(acc[mt][nt][i]);
        }
      }
  __syncthreads();

  const int hh = lane >> 4;            // head of col pair (2l, 2l+1)

  for (int it = 0; it < 4; it++) {
    const int lb = w * 4 + it;
    const int b = blockIdx.x * 16 + lb;
    unsigned short* hb = hps + lb * 6 * 146;   // this wave's exclusive rows

    float2 vm[6];
    float ein[6], ejn[6];
    #pragma unroll
    for (int m = 0; m < 6; m++) {
      unsigned int pk = *(const unsigned int*)&hb[m * 146 + lane * 2];
      vm[m].x = bf2f((unsigned short)(pk & 0xFFFFu));
      vm[m].y = bf2f((unsigned short)(pk >> 16));
      ein[m] = bf2f(hb[m * 146 + 128 + hh]);
      ejn[m] = bf2f(hb[m * 146 + 132 + hh]);
    }

    float g0[6], g1[6], zz[6];
    #pragma unroll
    for (int n = 0; n < 6; n++) {
      float ev[6]; float mx = -1e30f;
      #pragma unroll
      for (int m = 0; m < 6; m++) {
        float e = ein[n] + ejn[m];
        e = e > 0.f ? e : 0.2f * e;
        ev[m] = e; mx = fmaxf(mx, e);
      }
      float ss = 0.f;
      #pragma unroll
      for (int m = 0; m < 6; m++) { ev[m] = __expf(ev[m] - mx); ss += ev[m]; }
      const float inv = 1.0f / ss;
      float hn0 = 0.f, hn1 = 0.f;
      #pragma unroll
      for (int m = 0; m < 6; m++) {
        const float a = ev[m] * inv;
        hn0 += a * vm[m].x; hn1 += a * vm[m].y;
      }
      unsigned int xp = *(const unsigned int*)&xb[(size_t)b * 768 + n * 128 + lane * 2];
      float A0 = hn0 + bf2f((unsigned short)(xp & 0xFFFFu));
      float A1 = hn1 + bf2f((unsigned short)(xp >> 16));
      A0 = A0 > 0.f ? A0 : __expf(A0) - 1.0f;     // ELU, fast exp
      A1 = A1 > 0.f ? A1 : __expf(A1) - 1.0f;
      g0[n] = A0; g1[n] = A1;
      float zacc = A0 + A1;
      #pragma unroll
      for (int o = 32; o > 0; o >>= 1) zacc += __shfl_xor(zacc, o, 64);
      zz[n] = zacc * (1.0f / 128.0f);
    }

    float rr3[3];
    #pragma unroll
    for (int j = 0; j < 3; j++) {
      float a = se_b1[j];
      #pragma unroll
      for (int n = 0; n < 6; n++) a += zz[n] * se_w1[n * 3 + j];
      rr3[j] = fmaxf(a, 0.f);
    }
    float wse[6];
    #pragma unroll
    for (int n = 0; n < 6; n++) {
      float a = se_b2[n];
      #pragma unroll
      for (int j = 0; j < 3; j++) a += rr3[j] * se_w2[j * 6 + n];
      wse[n] = 1.0f / (1.0f + __expf(-a));
    }

    #pragma unroll
    for (int n = 0; n < 6; n++) {
      unsigned int pc = (unsigned int)f2bf(g0[n]) | ((unsigned int)f2bf(g1[n]) << 16);
      unsigned int ps = (unsigned int)f2bf(g0[n] * wse[n]) | ((unsigned int)f2bf(g1[n] * wse[n]) << 16);
      *(unsigned int*)&c[(size_t)b * 2688 + n * 128 + lane * 2] = pc;
      // s written IN PLACE into hps (this wave's rows, already read above)
      *(unsigned int*)&hb[n * 146 + lane * 2] = ps;
    }
  }

  // ---------------- fused vid GEMM + pairs (vectorized tail) ----------------
  __syncthreads();                     // all 16 batches' s resident in hps
  {
    const size_t B0 = (size_t)blockIdx.x * 16;
    const int pb0c[5] = {0, 5, 9, 12, 14};
    for (int z = 0; z < 5; z++) {
      floatx4 vacc[2];
      vacc[0] = (floatx4){0.f, 0.f, 0.f, 0.f};
      vacc[1] = (floatx4){0.f, 0.f, 0.f, 0.f};
      #pragma unroll
      for (int kk = 0; kk < 4; kk++) {
        // A-frag: s[batch=lr][feat z][k = kk*32 + lq*8 .. +8] via 4 aligned u32
        const int abase = (lr * 6 + z) * 146 + kk * 32 + lq * 8;
        uint4 au;
        au.x = *(const unsigned int*)&hps[abase + 0];
        au.y = *(const unsigned int*)&hps[abase + 2];
        au.z = *(const unsigned int*)&hps[abase + 4];
        au.w = *(const unsigned int*)&hps[abase + 6];
        const bf16x8 af = __builtin_bit_cast(bf16x8, au);
        #pragma unroll
        for (int nt = 0; nt < 2; nt++) {
          const int col = (w + nt * 4) * 16 + lr;        // output dim e
          const bf16x8 bv = __builtin_bit_cast(bf16x8,
            *(const uint4*)&biwt[z * 16384 + col * 128 + kk * 32 + lq * 8]);
          vacc[nt] = __builtin_amdgcn_mfma_f32_16x16x32_bf16(af, bv, vacc[nt], 0, 0, 0);
        }
      }
      __syncthreads();                 // prior z's vids readers done (no-op z=0)
      #pragma unroll
      for (int nt = 0; nt < 2; nt++) {
        const int cc = (w + nt * 4) * 16 + lr;
        #pragma unroll
        for (int i = 0; i < 4; i++)
          vids[(lq * 4 + i) * 132 + cc] = f2bf(vacc[nt][i]);
      }
      __syncthreads();                 // vids[z] resident
      const int npairs = 5 - z;
      const int tot = 16 * 32 * npairs;
      for (int e = t; e < tot; e += 256) {
        const int g  = e & 31;
        const int rp = e >> 5;
        const int p  = rp % npairs;
        const int r  = rp / npairs;
        ushort4 vv = *(const ushort4*)&vids[r * 132 + g * 4];
        const int hb2 = (r * 6 + z + 1 + p) * 146 + g * 4;
        unsigned int s01 = *(const unsigned int*)&hps[hb2];
        unsigned int s23 = *(const unsigned int*)&hps[hb2 + 2];
        ushort4 o;
        o.x = f2bf(bf2f(vv.x) * bf2f((unsigned short)(s01 & 0xFFFFu)));
        o.y = f2bf(bf2f(vv.y) * bf2f((unsigned short)(s01 >> 16)));
        o.z = f2bf(bf2f(vv.z) * bf2f((unsigned short)(s23 & 0xFFFFu)));
        o.w = f2bf(bf2f(vv.w) * bf2f((unsigned short)(s23 >> 16)));
        *(ushort4*)&c[(B0 + r) * 2688 + 768 + (size_t)(pb0c[z] + p) * 128 + g * 4] = o;
      }
    }
  }
}

// ---------------------------------------------------------------------------
// Fused MLP2 + bn+gelu + final 256-dot + sigmoid -> out.
// R6-BEST configuration: M=64 tile, 256 blocks, prefetch-1 double-buffer
// (2 slots x 40 KB).  R8's M=32/512-block variant regressed (+6 us): at
// M=32 every block still stages the full 256x64 B-panel, so doubling block
// count doubled B staging traffic.  Restored verbatim.
// ---------------------------------------------------------------------------
__global__ __launch_bounds__(512)
void k_mlp2out(const unsigned short* __restrict__ A, const unsigned short* __restrict__ Bt,
               const float* __restrict__ b2v, const float* __restrict__ bng,
               const float* __restrict__ bnb, const float* __restrict__ w3,
               const float* __restrict__ b3, float* __restrict__ out)
{
  __shared__ __align__(16) char smem[81920];     // 2 slots x 40960 B
  unsigned short* h2s = (unsigned short*)smem;   // alias slot 0 after K-loop

  const int t = threadIdx.x, lane = t & 63, w = t >> 6;
  const int lr = lane & 15, lq = lane >> 4;
  const int m0 = blockIdx.x * 64;

  floatx4 acc[4][2];
  #pragma unroll
  for (int a = 0; a < 4; a++)
    #pragma unroll
    for (int b = 0; b < 2; b++) acc[a][b] = (floatx4){0.f, 0.f, 0.f, 0.f};

  const int srow = lane >> 3;
  const int schk = (lane & 7) ^ srow;
  const int rb0 = w * 40;

  // slot s: As_ = 64x64 (4096 ush), Bs_ = 256x64 (16384 ush) -> 20480 ush
  auto STAGE = [&](int k0, int s) {
    unsigned short* As_ = (unsigned short*)smem + s * 20480;
    unsigned short* Bs_ = As_ + 4096;
    #pragma unroll
    for (int q = 0; q < 5; q++) {
      const int rb = rb0 + q * 8;
      if (rb < 64) ALOAD16(A + (size_t)(m0 + rb + srow) * 512 + k0 + schk * 8, As_ + rb * 64);
      else { const int rbb = rb - 64; ALOAD16(Bt + (size_t)(rbb + srow) * 512 + k0 + schk * 8, Bs_ + rbb * 64); }
    }
  };

  STAGE(0, 0);
  __syncthreads();                              // tile 0 resident

  for (int kt = 0; kt < 8; kt++) {
    const int cur = kt & 1;
    if (kt < 7) STAGE((kt + 1) * 64, cur ^ 1);  // prefetch next tile (in flight)
    const unsigned short* As = (const unsigned short*)smem + cur * 20480;
    const unsigned short* Bs = As + 4096;
    #pragma unroll
    for (int ko = 0; ko < 2; ko++) {
      bf16x8 af[4], bfv[2];
      #pragma unroll
      for (int mt = 0; mt < 4; mt++) {
        const int row = mt * 16 + lr;
        const int pc = (ko * 4 + lq) ^ (lr & 7);
        af[mt] = __builtin_bit_cast(bf16x8, *(const uint4*)&As[row * 64 + pc * 8]);
      }
      #pragma unroll
      for (int nt = 0; nt < 2; nt++) {
        const int row = w * 32 + nt * 16 + lr;
        const int pc = (ko * 4 + lq) ^ (lr & 7);
        bfv[nt] = __builtin_bit_cast(bf16x8, *(const uint4*)&Bs[row * 64 + pc * 8]);
      }
      #pragma unroll
      for (int mt = 0; mt < 4; mt++)
        #pragma unroll
        for (int nt = 0; nt < 2; nt++)
          acc[mt][nt] = __builtin_amdgcn_mfma_f32_16x16x32_bf16(af[mt], bfv[nt], acc[mt][nt], 0, 0, 0);
    }
    __syncthreads();                            // next tile landed; slot reusable
  }

  #pragma unroll
  for (int mt = 0; mt < 4; mt++)
    #pragma unroll
    for (int nt = 0; nt < 2; nt++)
      #pragma unroll
      for (int i = 0; i < 4; i++) {
        const int rr = mt * 16 + lq * 4 + i;
        const int cc = w * 32 + nt * 16 + lr;
        float tt = acc[mt][nt][i] + b2v[cc];
        tt = tt * (bng[cc] * 0.9999950000374997f) + bnb[cc];
        h2s[rr * 264 + cc] = f2bf(gelu_exact(tt));
      }
  __syncthreads();

  const float4 w4 = *(const float4*)&w3[lane * 4];
  #pragma unroll
  for (int rr = 0; rr < 8; rr++) {
    const int r = w * 8 + rr;
    ushort4 v = *(const ushort4*)&h2s[r * 264 + lane * 4];
    float a = bf2f(v.x) * w4.x + bf2f(v.y) * w4.y + bf2f(v.z) * w4.z + bf2f(v.w) * w4.w;
    #pragma unroll
    for (int o = 32; o > 0; o >>= 1) a += __shfl_xor(a, o, 64);
    if (lane == 0) out[m0 + r] = 1.0f / (1.0f + __expf(-(a + b3[0])));
  }
}

// ---------------------------------------------------------------------------
// Workspace layout (bytes).  sb buffer no longer used (vid fused into hpatt).
// ---------------------------------------------------------------------------
#define OFF_MMWT   0ull           // 32768
#define OFF_BIWT   65536ull       // 163840
#define OFF_W1T    229376ull      // 2752512
#define OFF_W2T    2981888ull     // 262144
#define OFF_IMMB   3244032ull     // 4194304
#define OFF_XB     7438336ull     // 25165824  (alias: h1 later)
#define OFF_SB     57769984ull    // 25165824 (unused after fusion)
#define OFF_C      82935808ull    // 88080384
#define OFF_IEMB   179404800ull   // 11739904 (fp8)
#define OFF_WALLT2 191144704ull   // 36864 -> total 191181568

extern "C" void kernel_launch(void* const* d_in, const int* in_sizes, int n_in,
                              void* d_out, int out_size, void* d_ws, size_t ws_size,
                              hipStream_t stream)
{
  const int*   item_id  = (const int*)  d_in[0];
  const float* item_mm  = (const float*)d_in[1];
  const int*   likes    = (const int*)  d_in[2];
  const int*   views    = (const int*)  d_in[3];
  const int*   item_seq = (const int*)  d_in[4];
  const float* item_emb = (const float*)d_in[5];
  const float* cate_emb = (const float*)d_in[6];
  const float* mm_w     = (const float*)d_in[7];
  const float* mm_b     = (const float*)d_in[8];
  const float* ln_g     = (const float*)d_in[9];
  const float* ln_b     = (const float*)d_in[10];
  const float* gnn_W    = (const float*)d_in[11];
  const float* gnn_a    = (const float*)d_in[12];
  const float* se_w1    = (const float*)d_in[13];
  const float* se_b1    = (const float*)d_in[14];
  const float* se_w2    = (const float*)d_in[15];
  const float* se_b2    = (const float*)d_in[16];
  const float* bi_W     = (const float*)d_in[17];
  const float* mlp_w1   = (const float*)d_in[18];
  const float* mlp_b1   = (const float*)d_in[19];
  const float* bn1_g    = (const float*)d_in[20];
  const float* bn1_b    = (const float*)d_in[21];
  const float* mlp_w2   = (const float*)d_in[22];
  const float* mlp_b2   = (const float*)d_in[23];
  const float* bn2_g    = (const float*)d_in[24];
  const float* bn2_b    = (const float*)d_in[25];
  const float* mlp_w3   = (const float*)d_in[26];
  const float* mlp_b3   = (const float*)d_in[27];
  float* out = (float*)d_out;

  char* ws = (char*)d_ws;
  unsigned short* mmwt   = (unsigned short*)(ws + OFF_MMWT);
  unsigned short* biwt   = (unsigned short*)(ws + OFF_BIWT);
  unsigned short* w1t    = (unsigned short*)(ws + OFF_W1T);
  unsigned short* w2t    = (unsigned short*)(ws + OFF_W2T);
  unsigned short* immb   = (unsigned short*)(ws + OFF_IMMB);
  unsigned short* xb     = (unsigned short*)(ws + OFF_XB);
  unsigned short* cbuf   = (unsigned short*)(ws + OFF_C);
  unsigned short* h1b    = (unsigned short*)(ws + OFF_XB);   // alias: xb dead after k_hpatt
  unsigned char*  iembf8 = (unsigned char*) (ws + OFF_IEMB);
  unsigned short* wallt2 = (unsigned short*)(ws + OFF_WALLT2);

  // 1. merged packs + transposes (item_emb -> fp8 e4m3 table)
  k_prep<<<2440, 256, 0, stream>>>(gnn_W, gnn_a, item_mm, item_emb,
                                   mlp_w1, mlp_w2, bi_W, mm_w,
                                   wallt2, immb, iembf8, w1t, w2t, biwt, mmwt);
  // 2. merged feature build (fp8 gathers) + mm GEMM/LN/GELU
  k_featmm<<<2304, 512, 0, stream>>>(item_id, likes, views, item_seq, iembf8, cate_emb,
                                     immb, mmwt, mm_b, ln_g, ln_b, xb);
  // 3. fused hp GEMM + attention + SE + vid GEMM + pairs -> c (full width)
  k_hpatt<<<1024, 256, 0, stream>>>(xb, wallt2, se_w1, se_b1, se_w2, se_b2,
                                    biwt, cbuf);
  // 4. MLP1: h1 = gelu(bn1(c @ w1 + b1)), 2-phase prefetch, dbuf LDS (R2)
  gemm_mlp1<<<dim3(4, 128), 512, 0, stream>>>(cbuf, w1t, h1b, mlp_b1, bn1_g, bn1_b);
  // 5. fused MLP2 + bn + gelu + dot(w3) + sigmoid -> out (R6: M=64, 256 blk)
  k_mlp2out<<<256, 512, 0, stream>>>(h1b, w2t, mlp_b2, bn2_g, bn2_b, mlp_w3, mlp_b3, out);
}

// Round 10
// 297.479 us; speedup vs baseline: 1.0370x; 1.0208x over previous
//
#include <hip/hip_runtime.h>
#include <hip/hip_bf16.h>
#include <cstdint>
#include <cstddef>

#define BB 16384

typedef float  floatx4 __attribute__((ext_vector_type(4)));
typedef float  floatx2 __attribute__((ext_vector_type(2)));
typedef __bf16 bf16x8  __attribute__((ext_vector_type(8)));

__device__ __forceinline__ unsigned short f2bf(float f) {
  union { float f; unsigned int u; } v; v.f = f;
  unsigned int r = v.u + 0x7FFFu + ((v.u >> 16) & 1u);
  return (unsigned short)(r >> 16);
}
__device__ __forceinline__ float bf2f(unsigned short h) {
  union { unsigned int u; float f; } v; v.u = ((unsigned int)h) << 16;
  return v.f;
}
__device__ __forceinline__ float gelu_exact(float x) {
  return 0.5f * x * (1.0f + erff(x * 0.7071067811865475f));
}
// decode 8 fp8-e4m3 (packed in uint2) -> 8 floats via HW cvt
__device__ __forceinline__ void fp8x8_to_f32(uint2 v, float* o) {
  floatx2 p0 = __builtin_amdgcn_cvt_pk_f32_fp8((int)v.x, false);
  floatx2 p1 = __builtin_amdgcn_cvt_pk_f32_fp8((int)v.x, true);
  floatx2 p2 = __builtin_amdgcn_cvt_pk_f32_fp8((int)v.y, false);
  floatx2 p3 = __builtin_amdgcn_cvt_pk_f32_fp8((int)v.y, true);
  o[0] = p0.x; o[1] = p0.y; o[2] = p1.x; o[3] = p1.y;
  o[4] = p2.x; o[5] = p2.y; o[6] = p3.x; o[7] = p3.y;
}

// async global->LDS, 16B per lane; LDS dest = wave-uniform base + lane*16
#define ALOAD16(g, l) \
  __builtin_amdgcn_global_load_lds((const __attribute__((address_space(1))) void*)(g), \
                                   (__attribute__((address_space(3))) void*)(l), 16, 0, 0)

// ---------------------------------------------------------------------------
// k_prep: MERGED pack + transposes.
//   blocks 0..2047   : grid-stride pack jobs
//     [wallt2 18432 scalar | immb 524288 vec4 | iembf8 1467488 8-float jobs]
//     boundaries: 18432 / 542720 / 2010208
//   blocks 2048..2439: LDS-tiled transposes (w1, w2, bi_W, mm_w)
// ---------------------------------------------------------------------------
__global__ __launch_bounds__(256)
void k_prep(const float* __restrict__ gnn_W, const float* __restrict__ gnn_a,
            const float* __restrict__ item_mm, const float* __restrict__ item_emb,
            const float* __restrict__ w1, const float* __restrict__ w2,
            const float* __restrict__ bi_W, const float* __restrict__ mm_w,
            unsigned short* __restrict__ wallt2, unsigned short* __restrict__ immb,
            unsigned char* __restrict__ iembf8,
            unsigned short* __restrict__ w1t, unsigned short* __restrict__ w2t,
            unsigned short* __restrict__ biwt, unsigned short* __restrict__ mmwt)
{
  __shared__ float tile[64][65];
  if (blockIdx.x < 2048) {
    const int total = 18432 + 524288 + 1467488;   // 2010208 jobs
    for (int id = blockIdx.x * 256 + threadIdx.x; id < total; id += 2048 * 256) {
      if (id < 18432) {                  // wallt2[n][k], n < 144
        int n = id / 128, k = id % 128;
        if (n < 128) {
          wallt2[id] = f2bf(gnn_W[(n >> 5) * 4096 + k * 32 + (n & 31)]);
        } else if (n < 136) {            // q1 (128..131) / q2 (132..135)
          int h = (n - 128) & 3;
          int off = (n < 132) ? 0 : 32;
          float s = 0.f;
          for (int o = 0; o < 32; o++)
            s += gnn_W[h * 4096 + k * 32 + o] * gnn_a[h * 64 + off + o];
          wallt2[id] = f2bf(s);
        } else {
          wallt2[id] = 0;
        }
      } else if (id < 542720) {          // immb cvt vec4 (524288 jobs)
        int l = id - 18432;
        float4 v = ((const float4*)item_mm)[l];
        ushort4 o; o.x = f2bf(v.x); o.y = f2bf(v.y); o.z = f2bf(v.z); o.w = f2bf(v.w);
        ((ushort4*)immb)[l] = o;
      } else {                           // iembf8 encode, 8 floats/job (1467488)
        int l = id - 542720;
        const float4 v0 = ((const float4*)item_emb)[l * 2];
        const float4 v1 = ((const float4*)item_emb)[l * 2 + 1];
        int lo = __builtin_amdgcn_cvt_pk_fp8_f32(v0.x, v0.y, 0, false);
        lo     = __builtin_amdgcn_cvt_pk_fp8_f32(v0.z, v0.w, lo, true);
        int hi = __builtin_amdgcn_cvt_pk_fp8_f32(v1.x, v1.y, 0, false);
        hi     = __builtin_amdgcn_cvt_pk_fp8_f32(v1.z, v1.w, hi, true);
        uint2 o; o.x = (unsigned int)lo; o.y = (unsigned int)hi;
        ((uint2*)iembf8)[l] = o;
      }
    }
  } else {
    int blk = blockIdx.x - 2048;
    const float* in; unsigned short* outp; int R, C, bx, by;
    if (blk < 336)      { in = w1; outp = w1t; R = 2688; C = 512; bx = blk % 8; by = blk / 8; }
    else if (blk < 368) { blk -= 336; in = w2; outp = w2t; R = 512; C = 256; bx = blk % 4; by = blk / 4; }
    else if (blk < 388) { blk -= 368; int f = blk / 4; int r2 = blk % 4;
                          in = bi_W + f * 16384; outp = biwt + f * 16384;
                          R = 128; C = 128; bx = r2 % 2; by = r2 / 2; }
    else                { blk -= 388; in = mm_w; outp = mmwt; R = 128; C = 128;
                          bx = blk % 2; by = blk / 2; }
    const int c0 = bx * 64, r0 = by * 64;
    const int lr = threadIdx.x >> 6;
    const int lc = threadIdx.x & 63;
    #pragma unroll
    for (int i = 0; i < 16; i++) {
      int r = lr + i * 4;
      tile[r][lc] = in[(size_t)(r0 + r) * C + c0 + lc];
    }
    __syncthreads();
    #pragma unroll
    for (int i = 0; i < 16; i++) {
      int c = lr + i * 4;
      outp[(size_t)(c0 + c) * R + r0 + lc] = f2bf(tile[lc][c]);
    }
  }
}

// ---------------------------------------------------------------------------
// k_featmm: MERGED feature build + mm GEMM/LN/GELU (disjoint xb rows).
//   blocks 0..2047   : feat — 8 batches/block (one wave each); quarter-wave
//                      fp8 gathers (8 B/lane covers a 128 B row with 16 lanes)
//   blocks 2048..2303: mmln — y = item_mm @ mm_w + b -> LN -> GELU -> xb row 4
// ---------------------------------------------------------------------------
__global__ __launch_bounds__(512)
void k_featmm(const int* __restrict__ item_id, const int* __restrict__ likes,
              const int* __restrict__ views, const int* __restrict__ item_seq,
              const unsigned char* __restrict__ iembf8, const float* __restrict__ cate_emb,
              const unsigned short* __restrict__ immb, const unsigned short* __restrict__ mmwt,
              const float* __restrict__ mm_b, const float* __restrict__ ln_g,
              const float* __restrict__ ln_b, unsigned short* __restrict__ xb)
{
  __shared__ __align__(16) char smem[64 * 130 * 4];    // mmln only
  const int t = threadIdx.x, lane = t & 63, w = t >> 6;

  if (blockIdx.x < 2048) {
    // ------------------ feat: one wave per batch row ------------------
    const int b = blockIdx.x * 8 + w;
    const int g = lane >> 4, l16 = lane & 15;
    const size_t base = (size_t)b * 768;
    const int li = likes[b], vi = views[b], id = item_id[b];

    const int ng = (g < 2) ? 13 : 12;
    int idxs[13];
    #pragma unroll
    for (int e = 0; e < 13; e++)
      idxs[e] = (e < ng) ? item_seq[b * 50 + g + 4 * e] : 0;

    float acc[8] = {0.f, 0.f, 0.f, 0.f, 0.f, 0.f, 0.f, 0.f};
    float cnt = 0.f;
    #pragma unroll
    for (int e = 0; e < 13; e++) {
      const int idx = idxs[e];
      if (idx != 0) {
        cnt += 1.0f;
        uint2 v = *(const uint2*)&iembf8[(size_t)idx * 128 + l16 * 8];
        float dv[8];
        fp8x8_to_f32(v, dv);
        #pragma unroll
        for (int k = 0; k < 8; k++) acc[k] += dv[k];
      }
    }
    #pragma unroll
    for (int k = 0; k < 8; k++) {
      acc[k] += __shfl_xor(acc[k], 16, 64);
      acc[k] += __shfl_xor(acc[k], 32, 64);
    }
    cnt += __shfl_xor(cnt, 16, 64);
    cnt += __shfl_xor(cnt, 32, 64);
    const float ic = 1.0f / fmaxf(cnt, 1.0f);

    *(unsigned int*)&xb[base + lane * 2] = 0u;          // row 0 zeros

    if (g == 0) {                                       // row 5: hist mean
      uint4 o;
      o.x = (unsigned int)f2bf(acc[0] * ic) | ((unsigned int)f2bf(acc[1] * ic) << 16);
      o.y = (unsigned int)f2bf(acc[2] * ic) | ((unsigned int)f2bf(acc[3] * ic) << 16);
      o.z = (unsigned int)f2bf(acc[4] * ic) | ((unsigned int)f2bf(acc[5] * ic) << 16);
      o.w = (unsigned int)f2bf(acc[6] * ic) | ((unsigned int)f2bf(acc[7] * ic) << 16);
      *(uint4*)&xb[base + 640 + l16 * 8] = o;
    } else if (g == 1) {                                // row 3: id (fp8 -> bf16)
      uint2 v = *(const uint2*)&iembf8[(size_t)id * 128 + l16 * 8];
      float dv[8];
      fp8x8_to_f32(v, dv);
      uint4 o;
      o.x = (unsigned int)f2bf(dv[0]) | ((unsigned int)f2bf(dv[1]) << 16);
      o.y = (unsigned int)f2bf(dv[2]) | ((unsigned int)f2bf(dv[3]) << 16);
      o.z = (unsigned int)f2bf(dv[4]) | ((unsigned int)f2bf(dv[5]) << 16);
      o.w = (unsigned int)f2bf(dv[6]) | ((unsigned int)f2bf(dv[7]) << 16);
      *(uint4*)&xb[base + 384 + l16 * 8] = o;
    } else {                                            // rows 1/2: like/view
      const int ci = (g == 2) ? li : vi;
      const float4 v0 = *(const float4*)&cate_emb[(size_t)ci * 128 + l16 * 8];
      const float4 v1 = *(const float4*)&cate_emb[(size_t)ci * 128 + l16 * 8 + 4];
      uint4 o;
      o.x = (unsigned int)f2bf(v0.x) | ((unsigned int)f2bf(v0.y) << 16);
      o.y = (unsigned int)f2bf(v0.z) | ((unsigned int)f2bf(v0.w) << 16);
      o.z = (unsigned int)f2bf(v1.x) | ((unsigned int)f2bf(v1.y) << 16);
      o.w = (unsigned int)f2bf(v1.z) | ((unsigned int)f2bf(v1.w) << 16);
      *(uint4*)&xb[base + 128 + (g - 2) * 128 + l16 * 8] = o;
    }
    return;
  }

  // ------------------ mmln: 64x128 GEMM + bias + LN + GELU ------------------
  unsigned short* As = (unsigned short*)smem;           // 64*64
  unsigned short* Bs = (unsigned short*)(smem + 8192);  // 128*64
  float* cls = (float*)smem;                            // 64*130 after barrier

  const int lr = lane & 15, lq = lane >> 4;
  const int m0 = (blockIdx.x - 2048) * 64;

  floatx4 acc[4];
  #pragma unroll
  for (int a = 0; a < 4; a++) acc[a] = (floatx4){0.f, 0.f, 0.f, 0.f};

  const int srow = lane >> 3;
  const int schk = (lane & 7) ^ srow;
  const int rb0 = w * 24;

  for (int k0 = 0; k0 < 128; k0 += 64) {
    __syncthreads();
    #pragma unroll
    for (int q = 0; q < 3; q++) {
      const int rb = rb0 + q * 8;
      if (rb < 64) ALOAD16(immb + (size_t)(m0 + rb + srow) * 128 + k0 + schk * 8, As + rb * 64);
      else { const int rbb = rb - 64; ALOAD16(mmwt + (size_t)(rbb + srow) * 128 + k0 + schk * 8, Bs + rbb * 64); }
    }
    __syncthreads();
    #pragma unroll
    for (int ko = 0; ko < 2; ko++) {
      bf16x8 af[4], bv;
      #pragma unroll
      for (int mt = 0; mt < 4; mt++) {
        const int row = mt * 16 + lr;
        const int pc = (ko * 4 + lq) ^ (lr & 7);
        af[mt] = __builtin_bit_cast(bf16x8, *(const uint4*)&As[row * 64 + pc * 8]);
      }
      {
        const int row = w * 16 + lr;
        const int pc = (ko * 4 + lq) ^ (lr & 7);
        bv = __builtin_bit_cast(bf16x8, *(const uint4*)&Bs[row * 64 + pc * 8]);
      }
      #pragma unroll
      for (int mt = 0; mt < 4; mt++)
        acc[mt] = __builtin_amdgcn_mfma_f32_16x16x32_bf16(af[mt], bv, acc[mt], 0, 0, 0);
    }
  }

  __syncthreads();
  #pragma unroll
  for (int mt = 0; mt < 4; mt++)
    #pragma unroll
    for (int i = 0; i < 4; i++) {
      const int rr = mt * 16 + lq * 4 + i;
      const int cc = w * 16 + lr;
      cls[rr * 130 + cc] = acc[mt][i] + mm_b[cc];
    }
  __syncthreads();

  const float2 g2 = *(const float2*)&ln_g[lane * 2];
  const float2 b2 = *(const float2*)&ln_b[lane * 2];
  #pragma unroll
  for (int rr = 0; rr < 8; rr++) {
    const int r = w * 8 + rr;
    float2 v = *(const float2*)&cls[r * 130 + lane * 2];
    float s = v.x + v.y, s2 = v.x * v.x + v.y * v.y;
    #pragma unroll
    for (int o = 32; o > 0; o >>= 1) { s += __shfl_xor(s, o, 64); s2 += __shfl_xor(s2, o, 64); }
    float mu  = s * (1.0f / 128.0f);
    float var = s2 * (1.0f / 128.0f) - mu * mu;
    float rs  = rsqrtf(var + 1e-5f);
    float t0 = gelu_exact((v.x - mu) * rs * g2.x + b2.x);
    float t1 = gelu_exact((v.y - mu) * rs * g2.y + b2.y);
    unsigned int pk = (unsigned int)f2bf(t0) | ((unsigned int)f2bf(t1) << 16);
    *(unsigned int*)&xb[(size_t)(m0 + r) * 768 + 512 + lane * 2] = pk;
  }
}

// ---------------------------------------------------------------------------
// MLP1 GEMM: h1 = gelu(bn1(c @ w1 + b1)).  128x128 tile, BK=64, 512 thr,
// 8 waves 2x4.  XOR-8 swizzled global_load_lds staging (0-conflict layout).
// R2-PROVEN: minimum 2-phase prefetch — double-buffered LDS (2 x 32 KB,
// 2 WG/CU), stage K-tile t+1 BEFORE computing tile t, single __syncthreads
// (vmcnt(0) drain) per K-tile placed AFTER compute.  ~48 us / MfmaUtil 40%
// = the documented 2-barrier-structure ceiling (913 TF).  Do not touch.
// ---------------------------------------------------------------------------
__global__ __launch_bounds__(512)
void gemm_mlp1(const unsigned short* __restrict__ A, const unsigned short* __restrict__ Bt,
               unsigned short* __restrict__ Cp,
               const float* __restrict__ bias, const float* __restrict__ bng,
               const float* __restrict__ bnb)
{
  int p = blockIdx.y * gridDim.x + blockIdx.x;
  int xcd = p & 7, slot = p >> 3;
  const int bx = slot % gridDim.x;
  const int by = xcd * (gridDim.y >> 3) + slot / gridDim.x;
  const int n0 = bx * 128;
  const int m0 = by * 128;

  __shared__ __align__(16) unsigned short lds[2 * 16384];   // 2 slots x 32 KB
  const int t = threadIdx.x, lane = t & 63, w = t >> 6;
  const int wm = w & 1, wn = w >> 1;          // 2 x 4
  const int lr = lane & 15, lq = lane >> 4;

  floatx4 acc[4][2];
  #pragma unroll
  for (int a = 0; a < 4; a++)
    #pragma unroll
    for (int b = 0; b < 2; b++) acc[a][b] = (floatx4){0.f, 0.f, 0.f, 0.f};

  const int srow = lane >> 3;
  const int schk = (lane & 7) ^ srow;
  const int rb0 = w * 32;

  // stage K-tile (k-offset k0) into LDS slot s
  auto STAGE = [&](int k0, int s) {
    unsigned short* Ad = lds + s * 16384;
    unsigned short* Bd = Ad + 8192;
    #pragma unroll
    for (int q = 0; q < 4; q++) {
      const int rb = rb0 + q * 8;
      if (rb < 128) {
        ALOAD16(A + (size_t)(m0 + rb + srow) * 2688 + k0 + schk * 8, Ad + rb * 64);
      } else {
        ALOAD16(Bt + (size_t)(n0 + rb - 128 + srow) * 2688 + k0 + schk * 8, Bd + (rb - 128) * 64);
      }
    }
  };

  STAGE(0, 0);
  __syncthreads();                              // tile 0 resident

  for (int kt = 0; kt < 42; kt++) {
    const int cur = kt & 1;
    if (kt < 41) STAGE((kt + 1) * 64, cur ^ 1); // prefetch next tile (in flight)
    const unsigned short* As = lds + cur * 16384;
    const unsigned short* Bs = As + 8192;
    #pragma unroll
    for (int ko = 0; ko < 2; ko++) {
      bf16x8 af[4], bfv[2];
      #pragma unroll
      for (int mt = 0; mt < 4; mt++) {
        const int row = wm * 64 + mt * 16 + lr;
        const int pc = (ko * 4 + lq) ^ (lr & 7);
        af[mt] = __builtin_bit_cast(bf16x8, *(const uint4*)&As[row * 64 + pc * 8]);
      }
      #pragma unroll
      for (int nt = 0; nt < 2; nt++) {
        const int row = wn * 32 + nt * 16 + lr;
        const int pc = (ko * 4 + lq) ^ (lr & 7);
        bfv[nt] = __builtin_bit_cast(bf16x8, *(const uint4*)&Bs[row * 64 + pc * 8]);
      }
      #pragma unroll
      for (int mt = 0; mt < 4; mt++)
        #pragma unroll
        for (int nt = 0; nt < 2; nt++)
          acc[mt][nt] = __builtin_amdgcn_mfma_f32_16x16x32_bf16(af[mt], bfv[nt], acc[mt][nt], 0, 0, 0);
    }
    __syncthreads();                            // drains vmcnt(0): next tile landed,
  }                                             // current slot free for re-stage

  #pragma unroll
  for (int mt = 0; mt < 4; mt++)
    #pragma unroll
    for (int nt = 0; nt < 2; nt++)
      #pragma unroll
      for (int i = 0; i < 4; i++) {
        const int cm = m0 + wm * 64 + mt * 16 + lq * 4 + i;
        const int cn = n0 + wn * 32 + nt * 16 + lr;
        float tt = acc[mt][nt][i] + bias[cn];
        tt = tt * (bng[cn] * 0.9999950000374997f) + bnb[cn];
        Cp[(size_t)cm * 512 + cn] = f2bf(gelu_exact(tt));
      }
}

// ---------------------------------------------------------------------------
// Fused: hp GEMM (96x144x128, ei/ej as fused columns 128..135) -> GAT
// attention + ELU + SE -> c[:, :768] + fused vid GEMM + pairs -> c[:, 768:].
// ROUND 10: 512 threads / 8 waves per block (was 256/4) — the prescribed
// latency-bound fix (occupancy 18.5%, no pipe saturated) never yet tried.
// Same 1024 blocks, same LDS, same phase structure & arithmetic; per-thread
// serial work halved, waves/CU doubled.  GEMM wave grid 2x4 (B-tiles
// tid = wn + 4*nt, nt<3, nt<2 || wn==0); attention 2 batches/wave; vid tail
// one 16-col strip/wave; epilogue stride 512.
// ---------------------------------------------------------------------------
__global__ __launch_bounds__(512)
void k_hpatt(const unsigned short* __restrict__ xb, const unsigned short* __restrict__ wallt2,
             const float* __restrict__ se_w1, const float* __restrict__ se_b1,
             const float* __restrict__ se_w2, const float* __restrict__ se_b2,
             const unsigned short* __restrict__ biwt,
             unsigned short* __restrict__ c)
{
  __shared__ __align__(16) char smem[34944];             // 30720 stage/hps + 4224 vids
  unsigned short* As = (unsigned short*)smem;            // 96*64  = 12288 B
  unsigned short* Bs = (unsigned short*)(smem + 12288);  // 144*64 = 18432 B
  unsigned short* hps = (unsigned short*)smem;           // 96*146 bf16 (alias)
  unsigned short* vids = (unsigned short*)(smem + 30720);// 16*132 bf16 vid[z] tile

  const int t = threadIdx.x, lane = t & 63, w = t >> 6;  // w in 0..7
  const int wm = w & 1, wn = w >> 1;                     // wm 0..1, wn 0..3
  const int lr = lane & 15, lq = lane >> 4;
  const int m0 = blockIdx.x * 96;

  floatx4 acc[3][3];
  #pragma unroll
  for (int a = 0; a < 3; a++)
    #pragma unroll
    for (int b = 0; b < 3; b++) acc[a][b] = (floatx4){0.f, 0.f, 0.f, 0.f};

  const int srow = lane >> 3;
  const int schk = (lane & 7) ^ srow;

  for (int k0 = 0; k0 < 128; k0 += 64) {
    __syncthreads();
    #pragma unroll
    for (int q = 0; q < 4; q++) {
      const int e = w + 8 * q;          // 30 issues: A rows 96 (12), B rows 144 (18)
      if (e < 30) {
        const int rb = e * 8;
        if (rb < 96) {
          ALOAD16(xb + (size_t)(m0 + rb + srow) * 128 + k0 + schk * 8, As + rb * 64);
        } else {
          const int rbb = rb - 96;
          ALOAD16(wallt2 + (size_t)(rbb + srow) * 128 + k0 + schk * 8, Bs + rbb * 64);
        }
      }
    }
    __syncthreads();
    #pragma unroll
    for (int ko = 0; ko < 2; ko++) {
      bf16x8 af[3];
      #pragma unroll
      for (int mt = 0; mt < 3; mt++) {
        const int row = wm * 48 + mt * 16 + lr;
        const int pc = (ko * 4 + lq) ^ (lr & 7);
        af[mt] = __builtin_bit_cast(bf16x8, *(const uint4*)&As[row * 64 + pc * 8]);
      }
      #pragma unroll
      for (int nt = 0; nt < 3; nt++) {
        if (nt < 2 || wn == 0) {
          const int tid = wn + 4 * nt;  // wn0: 0,4,8 ; wn1: 1,5 ; wn2: 2,6 ; wn3: 3,7
          const int row = tid * 16 + lr;
          const int pc = (ko * 4 + lq) ^ (lr & 7);
          bf16x8 bfv = __builtin_bit_cast(bf16x8, *(const uint4*)&Bs[row * 64 + pc * 8]);
          #pragma unroll
          for (int mt = 0; mt < 3; mt++)
            acc[mt][nt] = __builtin_amdgcn_mfma_f32_16x16x32_bf16(af[mt], bfv, acc[mt][nt], 0, 0, 0);
        }
      }
    }
  }

  __syncthreads();                     // staging dead; write bf16 hp tile (146 stride)
  #pragma unroll
  for (int mt = 0; mt < 3; mt++)
    #pragma unroll
    for (int nt = 0; nt < 3; nt++)
      if (nt < 2 || wn == 0) {
        const int tid = wn + 4 * nt;
        #pragma unroll
        for (int i = 0; i < 4; i++) {
          const int rr = wm * 48 + mt * 16 + lq * 4 + i;
          const int cc = tid * 16 + lr;
          hps[rr * 146 + cc] = f2bf(acc[mt][nt][i]);
        }
      }
  __syncthreads();

  const int hh = lane >> 4;            // head of col pair (2l, 2l+1)

  for (int it = 0; it < 2; it++) {
    const int lb = w * 2 + it;         // 0..15
    const int b = blockIdx.x * 16 + lb;
    unsigned short* hb = hps + lb * 6 * 146;   // this wave's exclusive rows

    float2 vm[6];
    float ein[6], ejn[6];
    #pragma unroll
    for (int m = 0; m < 6; m++) {
      unsigned int pk = *(const unsigned int*)&hb[m * 146 + lane * 2];
      vm[m].x = bf2f((unsigned short)(pk & 0xFFFFu));
      vm[m].y = bf2f((unsigned short)(pk >> 16));
      ein[m] = bf2f(hb[m * 146 + 128 + hh]);
      ejn[m] = bf2f(hb[m * 146 + 132 + hh]);
    }

    float g0[6], g1[6], zz[6];
    #pragma unroll
    for (int n = 0; n < 6; n++) {
      float ev[6]; float mx = -1e30f;
      #pragma unroll
      for (int m = 0; m < 6; m++) {
        float e = ein[n] + ejn[m];
        e = e > 0.f ? e : 0.2f * e;
        ev[m] = e; mx = fmaxf(mx, e);
      }
      float ss = 0.f;
      #pragma unroll
      for (int m = 0; m < 6; m++) { ev[m] = __expf(ev[m] - mx); ss += ev[m]; }
      const float inv = 1.0f / ss;
      float hn0 = 0.f, hn1 = 0.f;
      #pragma unroll
      for (int m = 0; m < 6; m++) {
        const float a = ev[m] * inv;
        hn0 += a * vm[m].x; hn1 += a * vm[m].y;
      }
      unsigned int xp = *(const unsigned int*)&xb[(size_t)b * 768 + n * 128 + lane * 2];
      float A0 = hn0 + bf2f((unsigned short)(xp & 0xFFFFu));
      float A1 = hn1 + bf2f((unsigned short)(xp >> 16));
      A0 = A0 > 0.f ? A0 : __expf(A0) - 1.0f;     // ELU, fast exp
      A1 = A1 > 0.f ? A1 : __expf(A1) - 1.0f;
      g0[n] = A0; g1[n] = A1;
      float zacc = A0 + A1;
      #pragma unroll
      for (int o = 32; o > 0; o >>= 1) zacc += __shfl_xor(zacc, o, 64);
      zz[n] = zacc * (1.0f / 128.0f);
    }

    float rr3[3];
    #pragma unroll
    for (int j = 0; j < 3; j++) {
      float a = se_b1[j];
      #pragma unroll
      for (int n = 0; n < 6; n++) a += zz[n] * se_w1[n * 3 + j];
      rr3[j] = fmaxf(a, 0.f);
    }
    float wse[6];
    #pragma unroll
    for (int n = 0; n < 6; n++) {
      float a = se_b2[n];
      #pragma unroll
      for (int j = 0; j < 3; j++) a += rr3[j] * se_w2[j * 6 + n];
      wse[n] = 1.0f / (1.0f + __expf(-a));
    }

    #pragma unroll
    for (int n = 0; n < 6; n++) {
      unsigned int pc = (unsigned int)f2bf(g0[n]) | ((unsigned int)f2bf(g1[n]) << 16);
      unsigned int ps = (unsigned int)f2bf(g0[n] * wse[n]) | ((unsigned int)f2bf(g1[n] * wse[n]) << 16);
      *(unsigned int*)&c[(size_t)b * 2688 + n * 128 + lane * 2] = pc;
      // s written IN PLACE into hps (this wave's rows, already read above)
      *(unsigned int*)&hb[n * 146 + lane * 2] = ps;
    }
  }

  // ---------------- fused vid GEMM + pairs (vectorized tail) ----------------
  __syncthreads();                     // all 16 batches' s resident in hps
  {
    const size_t B0 = (size_t)blockIdx.x * 16;
    const int pb0c[5] = {0, 5, 9, 12, 14};
    for (int z = 0; z < 5; z++) {
      floatx4 vacc = (floatx4){0.f, 0.f, 0.f, 0.f};
      #pragma unroll
      for (int kk = 0; kk < 4; kk++) {
        // A-frag: s[batch=lr][feat z][k = kk*32 + lq*8 .. +8] via 4 aligned u32
        const int abase = (lr * 6 + z) * 146 + kk * 32 + lq * 8;
        uint4 au;
        au.x = *(const unsigned int*)&hps[abase + 0];
        au.y = *(const unsigned int*)&hps[abase + 2];
        au.z = *(const unsigned int*)&hps[abase + 4];
        au.w = *(const unsigned int*)&hps[abase + 6];
        const bf16x8 af = __builtin_bit_cast(bf16x8, au);
        const int col = w * 16 + lr;                     // output dim e (one strip/wave)
        const bf16x8 bv = __builtin_bit_cast(bf16x8,
          *(const uint4*)&biwt[z * 16384 + col * 128 + kk * 32 + lq * 8]);
        vacc = __builtin_amdgcn_mfma_f32_16x16x32_bf16(af, bv, vacc, 0, 0, 0);
      }
      __syncthreads();                 // prior z's vids readers done (no-op z=0)
      {
        const int cc = w * 16 + lr;
        #pragma unroll
        for (int i = 0; i < 4; i++)
          vids[(lq * 4 + i) * 132 + cc] = f2bf(vacc[i]);
      }
      __syncthreads();                 // vids[z] resident
      const int npairs = 5 - z;
      const int tot = 16 * 32 * npairs;
      for (int e = t; e < tot; e += 512) {
        const int g  = e & 31;
        const int rp = e >> 5;
        const int p  = rp % npairs;
        const int r  = rp / npairs;
        ushort4 vv = *(const ushort4*)&vids[r * 132 + g * 4];
        const int hb2 = (r * 6 + z + 1 + p) * 146 + g * 4;
        unsigned int s01 = *(const unsigned int*)&hps[hb2];
        unsigned int s23 = *(const unsigned int*)&hps[hb2 + 2];
        ushort4 o;
        o.x = f2bf(bf2f(vv.x) * bf2f((unsigned short)(s01 & 0xFFFFu)));
        o.y = f2bf(bf2f(vv.y) * bf2f((unsigned short)(s01 >> 16)));
        o.z = f2bf(bf2f(vv.z) * bf2f((unsigned short)(s23 & 0xFFFFu)));
        o.w = f2bf(bf2f(vv.w) * bf2f((unsigned short)(s23 >> 16)));
        *(ushort4*)&c[(B0 + r) * 2688 + 768 + (size_t)(pb0c[z] + p) * 128 + g * 4] = o;
      }
    }
  }
}

// ---------------------------------------------------------------------------
// Fused MLP2 + bn+gelu + final 256-dot + sigmoid -> out.
// R6-BEST configuration: M=64 tile, 256 blocks, prefetch-1 double-buffer
// (2 slots x 40 KB).  R8's M=32/512-block variant regressed (+6 us).
// ---------------------------------------------------------------------------
__global__ __launch_bounds__(512)
void k_mlp2out(const unsigned short* __restrict__ A, const unsigned short* __restrict__ Bt,
               const float* __restrict__ b2v, const float* __restrict__ bng,
               const float* __restrict__ bnb, const float* __restrict__ w3,
               const float* __restrict__ b3, float* __restrict__ out)
{
  __shared__ __align__(16) char smem[81920];     // 2 slots x 40960 B
  unsigned short* h2s = (unsigned short*)smem;   // alias slot 0 after K-loop

  const int t = threadIdx.x, lane = t & 63, w = t >> 6;
  const int lr = lane & 15, lq = lane >> 4;
  const int m0 = blockIdx.x * 64;

  floatx4 acc[4][2];
  #pragma unroll
  for (int a = 0; a < 4; a++)
    #pragma unroll
    for (int b = 0; b < 2; b++) acc[a][b] = (floatx4){0.f, 0.f, 0.f, 0.f};

  const int srow = lane >> 3;
  const int schk = (lane & 7) ^ srow;
  const int rb0 = w * 40;

  // slot s: As_ = 64x64 (4096 ush), Bs_ = 256x64 (16384 ush) -> 20480 ush
  auto STAGE = [&](int k0, int s) {
    unsigned short* As_ = (unsigned short*)smem + s * 20480;
    unsigned short* Bs_ = As_ + 4096;
    #pragma unroll
    for (int q = 0; q < 5; q++) {
      const int rb = rb0 + q * 8;
      if (rb < 64) ALOAD16(A + (size_t)(m0 + rb + srow) * 512 + k0 + schk * 8, As_ + rb * 64);
      else { const int rbb = rb - 64; ALOAD16(Bt + (size_t)(rbb + srow) * 512 + k0 + schk * 8, Bs_ + rbb * 64); }
    }
  };

  STAGE(0, 0);
  __syncthreads();                              // tile 0 resident

  for (int kt = 0; kt < 8; kt++) {
    const int cur = kt & 1;
    if (kt < 7) STAGE((kt + 1) * 64, cur ^ 1);  // prefetch next tile (in flight)
    const unsigned short* As = (const unsigned short*)smem + cur * 20480;
    const unsigned short* Bs = As + 4096;
    #pragma unroll
    for (int ko = 0; ko < 2; ko++) {
      bf16x8 af[4], bfv[2];
      #pragma unroll
      for (int mt = 0; mt < 4; mt++) {
        const int row = mt * 16 + lr;
        const int pc = (ko * 4 + lq) ^ (lr & 7);
        af[mt] = __builtin_bit_cast(bf16x8, *(const uint4*)&As[row * 64 + pc * 8]);
      }
      #pragma unroll
      for (int nt = 0; nt < 2; nt++) {
        const int row = w * 32 + nt * 16 + lr;
        const int pc = (ko * 4 + lq) ^ (lr & 7);
        bfv[nt] = __builtin_bit_cast(bf16x8, *(const uint4*)&Bs[row * 64 + pc * 8]);
      }
      #pragma unroll
      for (int mt = 0; mt < 4; mt++)
        #pragma unroll
        for (int nt = 0; nt < 2; nt++)
          acc[mt][nt] = __builtin_amdgcn_mfma_f32_16x16x32_bf16(af[mt], bfv[nt], acc[mt][nt], 0, 0, 0);
    }
    __syncthreads();                            // next tile landed; slot reusable
  }

  #pragma unroll
  for (int mt = 0; mt < 4; mt++)
    #pragma unroll
    for (int nt = 0; nt < 2; nt++)
      #pragma unroll
      for (int i = 0; i < 4; i++) {
        const int rr = mt * 16 + lq * 4 + i;
        const int cc = w * 32 + nt * 16 + lr;
        float tt = acc[mt][nt][i] + b2v[cc];
        tt = tt * (bng[cc] * 0.9999950000374997f) + bnb[cc];
        h2s[rr * 264 + cc] = f2bf(gelu_exact(tt));
      }
  __syncthreads();

  const float4 w4 = *(const float4*)&w3[lane * 4];
  #pragma unroll
  for (int rr = 0; rr < 8; rr++) {
    const int r = w * 8 + rr;
    ushort4 v = *(const ushort4*)&h2s[r * 264 + lane * 4];
    float a = bf2f(v.x) * w4.x + bf2f(v.y) * w4.y + bf2f(v.z) * w4.z + bf2f(v.w) * w4.w;
    #pragma unroll
    for (int o = 32; o > 0; o >>= 1) a += __shfl_xor(a, o, 64);
    if (lane == 0) out[m0 + r] = 1.0f / (1.0f + __expf(-(a + b3[0])));
  }
}

// ---------------------------------------------------------------------------
// Workspace layout (bytes).  sb buffer no longer used (vid fused into hpatt).
// ---------------------------------------------------------------------------
#define OFF_MMWT   0ull           // 32768
#define OFF_BIWT   65536ull       // 163840
#define OFF_W1T    229376ull      // 2752512
#define OFF_W2T    2981888ull     // 262144
#define OFF_IMMB   3244032ull     // 4194304
#define OFF_XB     7438336ull     // 25165824  (alias: h1 later)
#define OFF_SB     57769984ull    // 25165824 (unused after fusion)
#define OFF_C      82935808ull    // 88080384
#define OFF_IEMB   179404800ull   // 11739904 (fp8)
#define OFF_WALLT2 191144704ull   // 36864 -> total 191181568

extern "C" void kernel_launch(void* const* d_in, const int* in_sizes, int n_in,
                              void* d_out, int out_size, void* d_ws, size_t ws_size,
                              hipStream_t stream)
{
  const int*   item_id  = (const int*)  d_in[0];
  const float* item_mm  = (const float*)d_in[1];
  const int*   likes    = (const int*)  d_in[2];
  const int*   views    = (const int*)  d_in[3];
  const int*   item_seq = (const int*)  d_in[4];
  const float* item_emb = (const float*)d_in[5];
  const float* cate_emb = (const float*)d_in[6];
  const float* mm_w     = (const float*)d_in[7];
  const float* mm_b     = (const float*)d_in[8];
  const float* ln_g     = (const float*)d_in[9];
  const float* ln_b     = (const float*)d_in[10];
  const float* gnn_W    = (const float*)d_in[11];
  const float* gnn_a    = (const float*)d_in[12];
  const float* se_w1    = (const float*)d_in[13];
  const float* se_b1    = (const float*)d_in[14];
  const float* se_w2    = (const float*)d_in[15];
  const float* se_b2    = (const float*)d_in[16];
  const float* bi_W     = (const float*)d_in[17];
  const float* mlp_w1   = (const float*)d_in[18];
  const float* mlp_b1   = (const float*)d_in[19];
  const float* bn1_g    = (const float*)d_in[20];
  const float* bn1_b    = (const float*)d_in[21];
  const float* mlp_w2   = (const float*)d_in[22];
  const float* mlp_b2   = (const float*)d_in[23];
  const float* bn2_g    = (const float*)d_in[24];
  const float* bn2_b    = (const float*)d_in[25];
  const float* mlp_w3   = (const float*)d_in[26];
  const float* mlp_b3   = (const float*)d_in[27];
  float* out = (float*)d_out;

  char* ws = (char*)d_ws;
  unsigned short* mmwt   = (unsigned short*)(ws + OFF_MMWT);
  unsigned short* biwt   = (unsigned short*)(ws + OFF_BIWT);
  unsigned short* w1t    = (unsigned short*)(ws + OFF_W1T);
  unsigned short* w2t    = (unsigned short*)(ws + OFF_W2T);
  unsigned short* immb   = (unsigned short*)(ws + OFF_IMMB);
  unsigned short* xb     = (unsigned short*)(ws + OFF_XB);
  unsigned short* cbuf   = (unsigned short*)(ws + OFF_C);
  unsigned short* h1b    = (unsigned short*)(ws + OFF_XB);   // alias: xb dead after k_hpatt
  unsigned char*  iembf8 = (unsigned char*) (ws + OFF_IEMB);
  unsigned short* wallt2 = (unsigned short*)(ws + OFF_WALLT2);

  // 1. merged packs + transposes (item_emb -> fp8 e4m3 table)
  k_prep<<<2440, 256, 0, stream>>>(gnn_W, gnn_a, item_mm, item_emb,
                                   mlp_w1, mlp_w2, bi_W, mm_w,
                                   wallt2, immb, iembf8, w1t, w2t, biwt, mmwt);
  // 2. merged feature build (fp8 gathers) + mm GEMM/LN/GELU
  k_featmm<<<2304, 512, 0, stream>>>(item_id, likes, views, item_seq, iembf8, cate_emb,
                                     immb, mmwt, mm_b, ln_g, ln_b, xb);
  // 3. fused hp GEMM + attention + SE + vid GEMM + pairs -> c, 8 waves/block
  k_hpatt<<<1024, 512, 0, stream>>>(xb, wallt2, se_w1, se_b1, se_w2, se_b2,
                                    biwt, cbuf);
  // 4. MLP1: h1 = gelu(bn1(c @ w1 + b1)), 2-phase prefetch, dbuf LDS (R2)
  gemm_mlp1<<<dim3(4, 128), 512, 0, stream>>>(cbuf, w1t, h1b, mlp_b1, bn1_g, bn1_b);
  // 5. fused MLP2 + bn + gelu + dot(w3) + sigmoid -> out (R6: M=64, 256 blk)
  k_mlp2out<<<256, 512, 0, stream>>>(h1b, w2t, mlp_b2, bn2_g, bn2_b, mlp_w3, mlp_b3, out);
}